// Round 2
// baseline (6609.225 us; speedup 1.0000x reference)
//
#include <hip/hip_runtime.h>
#include <hip/hip_bf16.h>
#include <cstdint>
#include <cstddef>

// ---------------------------------------------------------------------------
// GCNemb: 8-layer GCN. N=100000, E=3200000.
//   - CSR by target (histogram -> 1-block scan -> atomic-cursor fill).
//   - agg(xW) == agg(x)W: aggregate on smaller side per layer.
//   - L4->L5 fused in row chunks to avoid the n x 1024 intermediate.
//   - Runtime plan: fp32 activations if ws fits (~452MB), else bf16 storage
//     (~247MB) with fp32 arithmetic everywhere.
// ---------------------------------------------------------------------------

#define TPB 256
#define CHUNK 6400

__device__ inline float to_f(float v) { return v; }
__device__ inline float to_f(__hip_bfloat16 v) { return __bfloat162float(v); }
__device__ inline void from_f(float v, float& d) { d = v; }
__device__ inline void from_f(float v, __hip_bfloat16& d) { d = __float2bfloat16(v); }

__global__ void count_deg_kernel(const int* __restrict__ col, int* __restrict__ deg,
                                 int E, int n) {
    int e = blockIdx.x * blockDim.x + threadIdx.x;
    if (e < E) {
        int c = col[e];
        if ((unsigned)c < (unsigned)n) atomicAdd(&deg[c], 1);
    }
}

__global__ void dinv_kernel(const int* __restrict__ deg, float* __restrict__ dinv, int n) {
    int i = blockIdx.x * blockDim.x + threadIdx.x;
    if (i < n) dinv[i] = 1.0f / sqrtf((float)(deg[i] + 1));  // +1 self-loop
}

__global__ void scan_kernel(const int* __restrict__ deg, int* __restrict__ rowptr,
                            int* __restrict__ cursor, int n) {
    __shared__ int sums[1024];
    int tid = threadIdx.x;
    int chunk = (n + 1023) >> 10;
    int lo = tid * chunk;
    int hi = lo + chunk; if (hi > n) hi = n;
    int s = 0;
    for (int i = lo; i < hi; i++) s += deg[i];
    sums[tid] = s;
    __syncthreads();
    for (int off = 1; off < 1024; off <<= 1) {
        int v = (tid >= off) ? sums[tid - off] : 0;
        __syncthreads();
        sums[tid] += v;
        __syncthreads();
    }
    int run = (tid == 0) ? 0 : sums[tid - 1];
    for (int i = lo; i < hi; i++) {
        rowptr[i] = run; cursor[i] = run;
        run += deg[i];
    }
    if (tid == 1023) rowptr[n] = sums[1023];
}

__global__ void fill_csr_kernel(const int* __restrict__ row, const int* __restrict__ col,
                                int* __restrict__ cursor, int* __restrict__ srcs,
                                int E, int n) {
    int e = blockIdx.x * blockDim.x + threadIdx.x;
    if (e < E) {
        int c = col[e];
        if ((unsigned)c < (unsigned)n) {
            int pos = atomicAdd(&cursor[c], 1);
            if ((unsigned)pos < (unsigned)E) srcs[pos] = row[e];
        }
    }
}

// One wave per node; lane owns VEC contiguous features. width = 64*VEC.
template <typename T, int VEC>
__global__ __launch_bounds__(TPB) void agg_kernel(
        const T* __restrict__ x, T* __restrict__ out,
        const int* __restrict__ rowptr, const int* __restrict__ srcs,
        const float* __restrict__ dinv, const float* __restrict__ bias,
        int n, int relu) {
    const int d = 64 * VEC;
    int wid  = (blockIdx.x * blockDim.x + threadIdx.x) >> 6;
    int lane = threadIdx.x & 63;
    if (wid >= n) return;
    int start = rowptr[wid], end = rowptr[wid + 1];
    float acc[VEC];
#pragma unroll
    for (int j = 0; j < VEC; j++) acc[j] = 0.f;
    const int fo = lane * VEC;
    for (int e = start; e < end; e++) {
        int s = srcs[e];
        float ds = dinv[s];
        const T* __restrict__ xr = x + (size_t)s * d + fo;
#pragma unroll
        for (int j = 0; j < VEC; j++) acc[j] = fmaf(ds, to_f(xr[j]), acc[j]);
    }
    float di = dinv[wid];
    const T* __restrict__ xs = x + (size_t)wid * d + fo;
    T* __restrict__ orow = out + (size_t)wid * d + fo;
#pragma unroll
    for (int j = 0; j < VEC; j++) {
        float v = di * (acc[j] + di * to_f(xs[j]));
        if (bias) v += bias[fo + j];
        if (relu) v = fmaxf(v, 0.f);
        from_f(v, orow[j]);
    }
}

// Thread-per-node aggregation for tiny dims (fp32 in/out only).
template <int D>
__global__ __launch_bounds__(TPB) void agg_small_kernel(
        const float* __restrict__ x, float* __restrict__ out,
        const int* __restrict__ rowptr, const int* __restrict__ srcs,
        const float* __restrict__ dinv, const float* __restrict__ bias,
        int n, int relu) {
    int i = blockIdx.x * blockDim.x + threadIdx.x;
    if (i >= n) return;
    int start = rowptr[i], end = rowptr[i + 1];
    float acc[D];
#pragma unroll
    for (int j = 0; j < D; j++) acc[j] = 0.f;
    for (int e = start; e < end; e++) {
        int s = srcs[e];
        float ds = dinv[s];
#pragma unroll
        for (int j = 0; j < D; j++) acc[j] = fmaf(ds, x[(size_t)s * D + j], acc[j]);
    }
    float di = dinv[i];
#pragma unroll
    for (int j = 0; j < D; j++) {
        float v = di * (acc[j] + di * x[(size_t)i * D + j]);
        if (bias) v += bias[j];
        if (relu) v = fmaxf(v, 0.f);
        out[(size_t)i * D + j] = v;
    }
}

// C[nr x M] = A[nr x K] * W[K x M] (+bias)(+relu). fp32 compute; A/C storage typed.
#define BM 64
#define BN 64
#define BK 16
template <typename TA, typename TC>
__global__ __launch_bounds__(256) void gemm_kernel(
        const TA* __restrict__ A, const float* __restrict__ W,
        const float* __restrict__ bias, TC* __restrict__ C,
        int nr, int K, int M, int relu, int addbias) {
    __shared__ float As[BK][BM + 4];
    __shared__ float Bs[BK][BN + 4];
    int tid  = threadIdx.x;
    int row0 = blockIdx.x * BM;
    int col0 = blockIdx.y * BN;
    int rm = (tid >> 4) << 2;
    int rn = (tid & 15) << 2;
    float acc[4][4];
#pragma unroll
    for (int y = 0; y < 4; y++)
#pragma unroll
        for (int xj = 0; xj < 4; xj++) acc[y][xj] = 0.f;

    for (int kk = 0; kk < K; kk += BK) {
#pragma unroll
        for (int i = 0; i < 4; i++) {
            int idx = tid + i * 256;
            int k = idx & 15, r = idx >> 4;
            int gr = row0 + r, gk = kk + k;
            float v = 0.f;
            if (gr < nr && gk < K) v = to_f(A[(size_t)gr * K + gk]);
            As[k][r] = v;
        }
#pragma unroll
        for (int i = 0; i < 4; i++) {
            int idx = tid + i * 256;
            int k = idx >> 6, c = idx & 63;
            int gk = kk + k, gc = col0 + c;
            float v = 0.f;
            if (gk < K && gc < M) v = W[(size_t)gk * M + gc];
            Bs[k][c] = v;
        }
        __syncthreads();
#pragma unroll
        for (int k = 0; k < BK; k++) {
            float a[4], b[4];
#pragma unroll
            for (int j = 0; j < 4; j++) { a[j] = As[k][rm + j]; b[j] = Bs[k][rn + j]; }
#pragma unroll
            for (int y = 0; y < 4; y++)
#pragma unroll
                for (int xj = 0; xj < 4; xj++)
                    acc[y][xj] = fmaf(a[y], b[xj], acc[y][xj]);
        }
        __syncthreads();
    }
#pragma unroll
    for (int y = 0; y < 4; y++) {
        int gr = row0 + rm + y;
        if (gr >= nr) continue;
#pragma unroll
        for (int xj = 0; xj < 4; xj++) {
            int gc = col0 + rn + xj;
            if (gc >= M) continue;
            float v = acc[y][xj];
            if (addbias) v += bias[gc];
            if (relu) v = fmaxf(v, 0.f);
            from_f(v, C[(size_t)gr * M + gc]);
        }
    }
}

template <typename TA, typename TC>
static inline void launch_gemm(const TA* A, const float* W, const float* bias,
                               TC* C, int nr, int K, int M, int relu, int addbias,
                               hipStream_t stream) {
    dim3 grid((nr + BM - 1) / BM, (M + BN - 1) / BN);
    gemm_kernel<TA, TC><<<grid, 256, 0, stream>>>(A, W, bias, C, nr, K, M, relu, addbias);
}

static inline size_t al256(size_t x) { return (x + 255) & ~(size_t)255; }

template <typename T>
static void run_pipeline(const float* x, const int* rowv, const int* colv,
                         const float* const* Wt, const float* const* bt,
                         float* out, int n, int E, char* ws, hipStream_t stream) {
    size_t used = 0;
    auto carve = [&](size_t bytes) -> char* {
        char* r = ws + used; used += al256(bytes); return r;
    };
    int*   deg    = (int*)carve((size_t)n * 4);
    float* dinv   = (float*)carve((size_t)n * 4);
    int*   rowptr = (int*)carve((size_t)(n + 1) * 4);
    int*   cursor = (int*)carve((size_t)(n + 1) * 4);
    int*   srcs   = (int*)carve((size_t)E * 4);
    T*     bufA   = (T*)carve((size_t)n * 512 * sizeof(T));
    T*     bufB   = (T*)carve((size_t)n * 512 * sizeof(T));
    float* tmp    = (float*)carve((size_t)CHUNK * 1024 * 4);  // also reused as pre2 (n*2 fp32)
    float* agg3   = (float*)carve((size_t)n * 3 * 4);

    const int EB = (E + TPB - 1) / TPB;
    const int NB = (n + TPB - 1) / TPB;
    const int NW = (n + 3) / 4;

    // graph preprocessing
    hipMemsetAsync(deg, 0, (size_t)n * 4, stream);
    count_deg_kernel<<<EB, TPB, 0, stream>>>(colv, deg, E, n);
    dinv_kernel<<<NB, TPB, 0, stream>>>(deg, dinv, n);
    scan_kernel<<<1, 1024, 0, stream>>>(deg, rowptr, cursor, n);
    fill_csr_kernel<<<EB, TPB, 0, stream>>>(rowv, colv, cursor, srcs, E, n);

    // L0: 3 -> 64, agg-first on d=3
    agg_small_kernel<3><<<NB, TPB, 0, stream>>>(x, agg3, rowptr, srcs, dinv, nullptr, n, 0);
    launch_gemm<float, T>(agg3, Wt[0], bt[0], bufA, n, 3, 64, 1, 1, stream);

    // L1, L2: 64 -> 64
    agg_kernel<T, 1><<<NW, TPB, 0, stream>>>(bufA, bufB, rowptr, srcs, dinv, nullptr, n, 0);
    launch_gemm<T, T>(bufB, Wt[1], bt[1], bufA, n, 64, 64, 1, 1, stream);
    agg_kernel<T, 1><<<NW, TPB, 0, stream>>>(bufA, bufB, rowptr, srcs, dinv, nullptr, n, 0);
    launch_gemm<T, T>(bufB, Wt[2], bt[2], bufA, n, 64, 64, 1, 1, stream);

    // L3: 64 -> 128
    agg_kernel<T, 1><<<NW, TPB, 0, stream>>>(bufA, bufB, rowptr, srcs, dinv, nullptr, n, 0);
    launch_gemm<T, T>(bufB, Wt[3], bt[3], bufA, n, 64, 128, 1, 1, stream);

    // L4: agg on 128, then fused chunked (agg4 @ W4 -> relu -> @ W5) to avoid n x 1024
    agg_kernel<T, 2><<<NW, TPB, 0, stream>>>(bufA, bufB, rowptr, srcs, dinv, nullptr, n, 0);
    for (int r0 = 0; r0 < n; r0 += CHUNK) {
        int ch = n - r0; if (ch > CHUNK) ch = CHUNK;
        launch_gemm<T, float>(bufB + (size_t)r0 * 128, Wt[4], bt[4], tmp, ch, 128, 1024, 1, 1, stream);
        launch_gemm<float, T>(tmp, Wt[5], nullptr, bufA + (size_t)r0 * 512, ch, 1024, 512, 0, 0, stream);
    }
    // L5 epilogue: agg on 512, bias5 + relu
    agg_kernel<T, 8><<<NW, TPB, 0, stream>>>(bufA, bufB, rowptr, srcs, dinv, bt[5], n, 1);

    // L6: 512 -> 256 matmul-first
    launch_gemm<T, T>(bufB, Wt[6], nullptr, bufA, n, 512, 256, 0, 0, stream);
    agg_kernel<T, 4><<<NW, TPB, 0, stream>>>(bufA, bufB, rowptr, srcs, dinv, bt[6], n, 1);

    // L7: 256 -> 2 matmul-first, agg on d=2, no relu
    launch_gemm<T, float>(bufB, Wt[7], nullptr, tmp, n, 256, 2, 0, 0, stream);
    agg_small_kernel<2><<<NB, TPB, 0, stream>>>(tmp, out, rowptr, srcs, dinv, bt[7], n, 0);
}

template <typename T>
static size_t plan_bytes(int n, int E) {
    size_t s = 0;
    s += al256((size_t)n * 4) * 2;            // deg, dinv
    s += al256((size_t)(n + 1) * 4) * 2;      // rowptr, cursor
    s += al256((size_t)E * 4);                // srcs
    s += al256((size_t)n * 512 * sizeof(T)) * 2;  // bufA, bufB
    s += al256((size_t)CHUNK * 1024 * 4);     // tmp
    s += al256((size_t)n * 3 * 4);            // agg3
    return s;
}

extern "C" void kernel_launch(void* const* d_in, const int* in_sizes, int n_in,
                              void* d_out, int out_size, void* d_ws, size_t ws_size,
                              hipStream_t stream) {
    const float* x  = (const float*)d_in[0];
    const int*   ei = (const int*)d_in[1];
    const int E = in_sizes[1] / 2;
    const int n = in_sizes[0] / 3;
    const int* rowv = ei;
    const int* colv = ei + E;

    const float* Wt[8]; const float* bt[8];
    for (int i = 0; i < 8; i++) { Wt[i] = (const float*)d_in[2 + 2 * i]; bt[i] = (const float*)d_in[3 + 2 * i]; }

    if (plan_bytes<float>(n, E) <= ws_size) {
        run_pipeline<float>(x, rowv, colv, Wt, bt, (float*)d_out, n, E, (char*)d_ws, stream);
    } else if (plan_bytes<__hip_bfloat16>(n, E) <= ws_size) {
        run_pipeline<__hip_bfloat16>(x, rowv, colv, Wt, bt, (float*)d_out, n, E, (char*)d_ws, stream);
    }
    // else: workspace too small for any plan; leave output zeroed (will fail loudly)
}

// Round 3
// 3274.600 us; speedup vs baseline: 2.0183x; 2.0183x over previous
//
#include <hip/hip_runtime.h>
#include <hip/hip_bf16.h>
#include <cstdint>
#include <cstddef>

// ---------------------------------------------------------------------------
// GCNemb: 8-layer GCN. N=100000, E=3200000.
//   - CSR by target (histogram -> 1-block scan -> atomic-cursor fill).
//   - agg(xW) == agg(x)W: aggregate on smaller side per layer.
//   - All activations bf16 (storage), fp32 arithmetic. Measured r2: bf16
//     storage costs absmax 1.5e-5 vs threshold 6.56e-5.
//   - GEMMs L3..L6 on MFMA 16x16x32_bf16, 128x128 tile, global_load_lds.
//   - L4->L5 fused in row chunks (chunk sized from ws_size) to avoid n x 1024.
// ---------------------------------------------------------------------------

#define TPB 256

typedef short short8 __attribute__((ext_vector_type(8)));
typedef float f32x4 __attribute__((ext_vector_type(4)));

__device__ __forceinline__ float b2f(unsigned short u) {
    union { unsigned int i; float f; } c; c.i = ((unsigned int)u) << 16; return c.f;
}
__device__ __forceinline__ unsigned short f2b(float f) {
    __hip_bfloat16 h = __float2bfloat16(f);
    union { __hip_bfloat16 h; unsigned short u; } c; c.h = h; return c.u;
}

__device__ __forceinline__ void async_copy16(void* lds, const void* g) {
    __builtin_amdgcn_global_load_lds(
        (const __attribute__((address_space(1))) void*)g,
        (__attribute__((address_space(3))) void*)lds,
        16, 0, 0);
}

// ------------------------------ graph prep --------------------------------

__global__ void count_deg_kernel(const int* __restrict__ col, int* __restrict__ deg,
                                 int E, int n) {
    int e = blockIdx.x * blockDim.x + threadIdx.x;
    if (e < E) {
        int c = col[e];
        if ((unsigned)c < (unsigned)n) atomicAdd(&deg[c], 1);
    }
}

__global__ void dinv_kernel(const int* __restrict__ deg, float* __restrict__ dinv, int n) {
    int i = blockIdx.x * blockDim.x + threadIdx.x;
    if (i < n) dinv[i] = 1.0f / sqrtf((float)(deg[i] + 1));  // +1 self-loop
}

__global__ void scan_kernel(const int* __restrict__ deg, int* __restrict__ rowptr,
                            int* __restrict__ cursor, int n) {
    __shared__ int sums[1024];
    int tid = threadIdx.x;
    int chunk = (n + 1023) >> 10;
    int lo = tid * chunk;
    int hi = lo + chunk; if (hi > n) hi = n;
    int s = 0;
    for (int i = lo; i < hi; i++) s += deg[i];
    sums[tid] = s;
    __syncthreads();
    for (int off = 1; off < 1024; off <<= 1) {
        int v = (tid >= off) ? sums[tid - off] : 0;
        __syncthreads();
        sums[tid] += v;
        __syncthreads();
    }
    int run = (tid == 0) ? 0 : sums[tid - 1];
    for (int i = lo; i < hi; i++) {
        rowptr[i] = run; cursor[i] = run;
        run += deg[i];
    }
    if (tid == 1023) rowptr[n] = sums[1023];
}

__global__ void fill_csr_kernel(const int* __restrict__ row, const int* __restrict__ col,
                                int* __restrict__ cursor, int* __restrict__ srcs,
                                int E, int n) {
    int e = blockIdx.x * blockDim.x + threadIdx.x;
    if (e < E) {
        int c = col[e];
        if ((unsigned)c < (unsigned)n) {
            int pos = atomicAdd(&cursor[c], 1);
            if ((unsigned)pos < (unsigned)E) srcs[pos] = row[e];
        }
    }
}

// weight prep: W[K x M] fp32 -> Wt[M x K] bf16
__global__ void convert_wt_kernel(const float* __restrict__ W, unsigned short* __restrict__ Wt,
                                  int K, int M) {
    int idx = blockIdx.x * blockDim.x + threadIdx.x;
    if (idx < K * M) {
        int k = idx / M, m = idx % M;
        Wt[(size_t)m * K + k] = f2b(W[idx]);
    }
}

// ----------------------------- aggregation --------------------------------

template <int VEC> struct Pack;
template <> struct Pack<1> { using T = unsigned short; };
template <> struct Pack<2> { using T = unsigned int; };
template <> struct Pack<4> { using T = uint2; };
template <> struct Pack<8> { using T = uint4; };

// One wave per node; lane owns VEC contiguous bf16 features. width = 64*VEC.
template <int VEC>
__global__ __launch_bounds__(TPB) void agg_bf16_kernel(
        const unsigned short* __restrict__ x, unsigned short* __restrict__ out,
        const int* __restrict__ rowptr, const int* __restrict__ srcs,
        const float* __restrict__ dinv, const float* __restrict__ bias,
        int n, int relu) {
    using P = typename Pack<VEC>::T;
    const int d = 64 * VEC;
    int wid  = (blockIdx.x * blockDim.x + threadIdx.x) >> 6;
    int lane = threadIdx.x & 63;
    if (wid >= n) return;
    int start = rowptr[wid], end = rowptr[wid + 1];
    float acc[VEC];
#pragma unroll
    for (int j = 0; j < VEC; j++) acc[j] = 0.f;
    const int fo = lane * VEC;
    union { P v; unsigned short u[VEC]; } ld;
    for (int e = start; e < end; e++) {
        int s = srcs[e];
        float ds = dinv[s];
        ld.v = *(const P*)(x + (size_t)s * d + fo);
#pragma unroll
        for (int j = 0; j < VEC; j++) acc[j] = fmaf(ds, b2f(ld.u[j]), acc[j]);
    }
    float di = dinv[wid];
    ld.v = *(const P*)(x + (size_t)wid * d + fo);
    union { P v; unsigned short u[VEC]; } st;
#pragma unroll
    for (int j = 0; j < VEC; j++) {
        float v = di * (acc[j] + di * b2f(ld.u[j]));
        if (bias) v += bias[fo + j];
        if (relu) v = fmaxf(v, 0.f);
        st.u[j] = f2b(v);
    }
    *(P*)(out + (size_t)wid * d + fo) = st.v;
}

// Thread-per-node aggregation for tiny dims, fp32 in/out.
template <int D>
__global__ __launch_bounds__(TPB) void agg_small_kernel(
        const float* __restrict__ x, float* __restrict__ out,
        const int* __restrict__ rowptr, const int* __restrict__ srcs,
        const float* __restrict__ dinv, const float* __restrict__ bias,
        int n, int relu) {
    int i = blockIdx.x * blockDim.x + threadIdx.x;
    if (i >= n) return;
    int start = rowptr[i], end = rowptr[i + 1];
    float acc[D];
#pragma unroll
    for (int j = 0; j < D; j++) acc[j] = 0.f;
    for (int e = start; e < end; e++) {
        int s = srcs[e];
        float ds = dinv[s];
#pragma unroll
        for (int j = 0; j < D; j++) acc[j] = fmaf(ds, x[(size_t)s * D + j], acc[j]);
    }
    float di = dinv[i];
#pragma unroll
    for (int j = 0; j < D; j++) {
        float v = di * (acc[j] + di * x[(size_t)i * D + j]);
        if (bias) v += bias[j];
        if (relu) v = fmaxf(v, 0.f);
        out[(size_t)i * D + j] = v;
    }
}

// ------------------------------ VALU GEMM ---------------------------------
// C[nr x M] = A[nr x K] * W[K x M] (+bias)(+relu). fp32 compute, W fp32.
__device__ inline float to_f(float v) { return v; }
__device__ inline float to_f(__hip_bfloat16 v) { return __bfloat162float(v); }
__device__ inline void from_f(float v, float& d) { d = v; }
__device__ inline void from_f(float v, __hip_bfloat16& d) { d = __float2bfloat16(v); }

#define BM 64
#define BN 64
#define BK 16
template <typename TA, typename TC>
__global__ __launch_bounds__(256) void gemm_valu_kernel(
        const TA* __restrict__ A, const float* __restrict__ W,
        const float* __restrict__ bias, TC* __restrict__ C,
        int nr, int K, int M, int relu, int addbias) {
    __shared__ float As[BK][BM + 4];
    __shared__ float Bs[BK][BN + 4];
    int tid  = threadIdx.x;
    int row0 = blockIdx.x * BM;
    int col0 = blockIdx.y * BN;
    int rm = (tid >> 4) << 2;
    int rn = (tid & 15) << 2;
    float acc[4][4];
#pragma unroll
    for (int y = 0; y < 4; y++)
#pragma unroll
        for (int xj = 0; xj < 4; xj++) acc[y][xj] = 0.f;

    for (int kk = 0; kk < K; kk += BK) {
#pragma unroll
        for (int i = 0; i < 4; i++) {
            int idx = tid + i * 256;
            int k = idx & 15, r = idx >> 4;
            int gr = row0 + r, gk = kk + k;
            float v = 0.f;
            if (gr < nr && gk < K) v = to_f(A[(size_t)gr * K + gk]);
            As[k][r] = v;
        }
#pragma unroll
        for (int i = 0; i < 4; i++) {
            int idx = tid + i * 256;
            int k = idx >> 6, c = idx & 63;
            int gk = kk + k, gc = col0 + c;
            float v = 0.f;
            if (gk < K && gc < M) v = W[(size_t)gk * M + gc];
            Bs[k][c] = v;
        }
        __syncthreads();
#pragma unroll
        for (int k = 0; k < BK; k++) {
            float a[4], b[4];
#pragma unroll
            for (int j = 0; j < 4; j++) { a[j] = As[k][rm + j]; b[j] = Bs[k][rn + j]; }
#pragma unroll
            for (int y = 0; y < 4; y++)
#pragma unroll
                for (int xj = 0; xj < 4; xj++)
                    acc[y][xj] = fmaf(a[y], b[xj], acc[y][xj]);
        }
        __syncthreads();
    }
#pragma unroll
    for (int y = 0; y < 4; y++) {
        int gr = row0 + rm + y;
        if (gr >= nr) continue;
#pragma unroll
        for (int xj = 0; xj < 4; xj++) {
            int gc = col0 + rn + xj;
            if (gc >= M) continue;
            float v = acc[y][xj];
            if (addbias) v += bias[gc];
            if (relu) v = fmaxf(v, 0.f);
            from_f(v, C[(size_t)gr * M + gc]);
        }
    }
}

template <typename TA, typename TC>
static inline void launch_gemm_valu(const TA* A, const float* W, const float* bias,
                                    TC* C, int nr, int K, int M, int relu, int addbias,
                                    hipStream_t stream) {
    dim3 grid((nr + BM - 1) / BM, (M + BN - 1) / BN);
    gemm_valu_kernel<TA, TC><<<grid, 256, 0, stream>>>(A, W, bias, C, nr, K, M, relu, addbias);
}

// ------------------------------ MFMA GEMM ---------------------------------
// C[nr x M] = A[nr x K](bf16) * Wt[M x K](bf16, pre-transposed) (+bias fp32)(+relu)
// 128x128 tile, BK=32, 256 threads = 2x2 waves, each wave 64x64 = 4x4 frags
// of v_mfma_f32_16x16x32_bf16. Requires K%32==0 and M%128==0; nr guarded.
__global__ __launch_bounds__(256) void gemm_mfma_kernel(
        const unsigned short* __restrict__ A, const unsigned short* __restrict__ Wt,
        const float* __restrict__ bias, unsigned short* __restrict__ C,
        int nr, int K, int M, int relu, int addbias) {
    __shared__ alignas(16) short As[128 * 32];
    __shared__ alignas(16) short Bs[128 * 32];
    const int tid  = threadIdx.x;
    const int w    = tid >> 6;      // wave 0..3
    const int lane = tid & 63;
    const int wr   = w >> 1;        // wave row 0..1 (64 rows each)
    const int wc   = w & 1;         // wave col 0..1 (64 cols each)
    const int row0 = blockIdx.x * 128;
    const int col0 = blockIdx.y * 128;

    f32x4 acc[4][4];
#pragma unroll
    for (int i = 0; i < 4; i++)
#pragma unroll
        for (int j = 0; j < 4; j++) acc[i][j] = {0.f, 0.f, 0.f, 0.f};

    const int lrow   = lane >> 2;        // 0..15: row within a 16-row group
    const int lcolB  = (lane & 3) * 16;  // byte offset within a 64B row
    const int fm     = lane & 15;        // frag row/col within 16
    const int fq     = lane >> 4;        // k-octet 0..3

    for (int kk = 0; kk < K; kk += 32) {
        // stage A tile: wave w -> rows w*32 .. w*32+31 (2 instrs x 16 rows)
#pragma unroll
        for (int i = 0; i < 2; i++) {
            int r = w * 32 + i * 16 + lrow;
            int grow = row0 + r;
            const char* g = (const char*)A + ((size_t)grow * K + kk) * 2 + lcolB;
            short* lds = &As[(w * 32 + i * 16) * 32];
            if (grow < nr) async_copy16(lds, g);
        }
        // stage B tile (Wt rows are C cols; M%128==0 so never OOB)
#pragma unroll
        for (int i = 0; i < 2; i++) {
            int r = w * 32 + i * 16 + lrow;
            int gcol = col0 + r;
            const char* g = (const char*)Wt + ((size_t)gcol * K + kk) * 2 + lcolB;
            short* lds = &Bs[(w * 32 + i * 16) * 32];
            async_copy16(lds, g);
        }
        __syncthreads();  // drains vmcnt for global_load_lds

        short8 a[4], b[4];
#pragma unroll
        for (int i = 0; i < 4; i++) {
            a[i] = *(const short8*)&As[(wr * 64 + i * 16 + fm) * 32 + fq * 8];
            b[i] = *(const short8*)&Bs[(wc * 64 + i * 16 + fm) * 32 + fq * 8];
        }
#pragma unroll
        for (int mi = 0; mi < 4; mi++)
#pragma unroll
            for (int ni = 0; ni < 4; ni++)
                acc[mi][ni] = __builtin_amdgcn_mfma_f32_16x16x32_bf16(
                    a[mi], b[ni], acc[mi][ni], 0, 0, 0);
        __syncthreads();
    }

    // epilogue: C/D layout col=lane&15, row=(lane>>4)*4+reg  [m89-verified]
#pragma unroll
    for (int mi = 0; mi < 4; mi++) {
#pragma unroll
        for (int r = 0; r < 4; r++) {
            int row = row0 + wr * 64 + mi * 16 + fq * 4 + r;
            if (row >= nr) continue;
            size_t rb = (size_t)row * M;
#pragma unroll
            for (int ni = 0; ni < 4; ni++) {
                int col = col0 + wc * 64 + ni * 16 + fm;
                float v = acc[mi][ni][r];
                if (addbias) v += bias[col];
                if (relu) v = fmaxf(v, 0.f);
                C[rb + col] = f2b(v);
            }
        }
    }
}

static inline void launch_gemm_mfma(const unsigned short* A, const unsigned short* Wt,
                                    const float* bias, unsigned short* C,
                                    int nr, int K, int M, int relu, int addbias,
                                    hipStream_t stream) {
    dim3 grid((nr + 127) / 128, M / 128);
    gemm_mfma_kernel<<<grid, 256, 0, stream>>>(A, Wt, bias, C, nr, K, M, relu, addbias);
}

// ------------------------------- driver -----------------------------------

static inline size_t al256(size_t x) { return (x + 255) & ~(size_t)255; }

extern "C" void kernel_launch(void* const* d_in, const int* in_sizes, int n_in,
                              void* d_out, int out_size, void* d_ws, size_t ws_size,
                              hipStream_t stream) {
    const float* x  = (const float*)d_in[0];
    const int*   ei = (const int*)d_in[1];
    const int E = in_sizes[1] / 2;
    const int n = in_sizes[0] / 3;
    const int* rowv = ei;        // sources
    const int* colv = ei + E;    // targets

    const float* Wf[8]; const float* bt[8];
    for (int i = 0; i < 8; i++) { Wf[i] = (const float*)d_in[2 + 2 * i]; bt[i] = (const float*)d_in[3 + 2 * i]; }

    // workspace carve-out (bf16 plan, ~247 MB; ws_size known >= that from r2)
    char* p = (char*)d_ws;
    size_t used = 0;
    auto carve = [&](size_t bytes) -> char* {
        char* r = p + used; used += al256(bytes); return r;
    };
    int*   deg    = (int*)carve((size_t)n * 4);
    float* dinv   = (float*)carve((size_t)n * 4);
    int*   rowptr = (int*)carve((size_t)(n + 1) * 4);
    int*   cursor = (int*)carve((size_t)(n + 1) * 4);
    int*   srcs   = (int*)carve((size_t)E * 4);
    unsigned short* bufA = (unsigned short*)carve((size_t)n * 512 * 2);
    unsigned short* bufB = (unsigned short*)carve((size_t)n * 512 * 2);
    // transposed bf16 weights for MFMA layers 3..6
    const size_t wt3e = 64 * 128, wt4e = 128 * 1024, wt5e = 1024 * 512, wt6e = 512 * 256;
    unsigned short* wt3 = (unsigned short*)carve((wt3e + wt4e + wt5e + wt6e) * 2);
    unsigned short* wt4 = wt3 + wt3e;
    unsigned short* wt5 = wt4 + wt4e;
    unsigned short* wt6 = wt5 + wt5e;
    // tmp: sized from remaining ws; holds CHUNK x 1024 bf16, also n x 3 fp32
    // (agg3) and n x 2 fp32 (L7 pre-agg) at other times.
    size_t avail = (ws_size > used) ? (ws_size - used) : 0;
    int chunk = (int)(avail / (1024 * 2));
    if (chunk > n) chunk = n;
    if (chunk < 1024) chunk = 1024;  // floor (guaranteed to fit: ws >= 247MB)
    char* tmp_raw = carve((size_t)chunk * 1024 * 2);
    unsigned short* tmpb = (unsigned short*)tmp_raw;
    float* tmpf = (float*)tmp_raw;

    const int EB = (E + TPB - 1) / TPB;
    const int NB = (n + TPB - 1) / TPB;
    const int NW = (n + 3) / 4;  // blocks for wave-per-node kernels

    // ---- graph preprocessing ----
    hipMemsetAsync(deg, 0, (size_t)n * 4, stream);
    count_deg_kernel<<<EB, TPB, 0, stream>>>(colv, deg, E, n);
    dinv_kernel<<<NB, TPB, 0, stream>>>(deg, dinv, n);
    scan_kernel<<<1, 1024, 0, stream>>>(deg, rowptr, cursor, n);
    fill_csr_kernel<<<EB, TPB, 0, stream>>>(rowv, colv, cursor, srcs, E, n);

    // ---- weight prep (transpose + bf16) for MFMA layers ----
    convert_wt_kernel<<<(int)((wt3e + 255) / 256), 256, 0, stream>>>(Wf[3], wt3, 64, 128);
    convert_wt_kernel<<<(int)((wt4e + 255) / 256), 256, 0, stream>>>(Wf[4], wt4, 128, 1024);
    convert_wt_kernel<<<(int)((wt5e + 255) / 256), 256, 0, stream>>>(Wf[5], wt5, 1024, 512);
    convert_wt_kernel<<<(int)((wt6e + 255) / 256), 256, 0, stream>>>(Wf[6], wt6, 512, 256);

    // ---- L0: 3 -> 64 (agg-first d=3, VALU gemm) ----
    agg_small_kernel<3><<<NB, TPB, 0, stream>>>(x, tmpf, rowptr, srcs, dinv, nullptr, n, 0);
    launch_gemm_valu<float, __hip_bfloat16>(tmpf, Wf[0], bt[0], (__hip_bfloat16*)bufA,
                                            n, 3, 64, 1, 1, stream);

    // ---- L1, L2: 64 -> 64 (agg-first, VALU gemm: M=64 not MFMA-tileable) ----
    agg_bf16_kernel<1><<<NW, TPB, 0, stream>>>(bufA, bufB, rowptr, srcs, dinv, nullptr, n, 0);
    launch_gemm_valu<__hip_bfloat16, __hip_bfloat16>((const __hip_bfloat16*)bufB, Wf[1], bt[1],
                                                     (__hip_bfloat16*)bufA, n, 64, 64, 1, 1, stream);
    agg_bf16_kernel<1><<<NW, TPB, 0, stream>>>(bufA, bufB, rowptr, srcs, dinv, nullptr, n, 0);
    launch_gemm_valu<__hip_bfloat16, __hip_bfloat16>((const __hip_bfloat16*)bufB, Wf[2], bt[2],
                                                     (__hip_bfloat16*)bufA, n, 64, 64, 1, 1, stream);

    // ---- L3: 64 -> 128 (agg-first, MFMA) ----
    agg_bf16_kernel<1><<<NW, TPB, 0, stream>>>(bufA, bufB, rowptr, srcs, dinv, nullptr, n, 0);
    launch_gemm_mfma(bufB, wt3, bt[3], bufA, n, 64, 128, 1, 1, stream);

    // ---- L4+L5 fused: agg on 128, then chunked (h=relu(.@W4+b4)) @ W5 ----
    agg_bf16_kernel<2><<<NW, TPB, 0, stream>>>(bufA, bufB, rowptr, srcs, dinv, nullptr, n, 0);
    for (int r0 = 0; r0 < n; r0 += chunk) {
        int ch = n - r0; if (ch > chunk) ch = chunk;
        launch_gemm_mfma(bufB + (size_t)r0 * 128, wt4, bt[4], tmpb, ch, 128, 1024, 1, 1, stream);
        launch_gemm_mfma(tmpb, wt5, nullptr, bufA + (size_t)r0 * 512, ch, 1024, 512, 0, 0, stream);
    }
    // L5 epilogue: agg on 512, bias5 + relu
    agg_bf16_kernel<8><<<NW, TPB, 0, stream>>>(bufA, bufB, rowptr, srcs, dinv, bt[5], n, 1);

    // ---- L6: 512 -> 256 (matmul-first MFMA, agg on 256) ----
    launch_gemm_mfma(bufB, wt6, nullptr, bufA, n, 512, 256, 0, 0, stream);
    agg_bf16_kernel<4><<<NW, TPB, 0, stream>>>(bufA, bufB, rowptr, srcs, dinv, bt[6], n, 1);

    // ---- L7: 256 -> 2 (VALU gemm, agg on d=2, no relu) ----
    launch_gemm_valu<__hip_bfloat16, float>((const __hip_bfloat16*)bufB, Wf[7], nullptr, tmpf,
                                            n, 256, 2, 0, 0, stream);
    agg_small_kernel<2><<<NB, TPB, 0, stream>>>(tmpf, (float*)d_out, rowptr, srcs, dinv, bt[7], n, 0);
}

// Round 4
// 2346.630 us; speedup vs baseline: 2.8165x; 1.3954x over previous
//
#include <hip/hip_runtime.h>
#include <hip/hip_bf16.h>
#include <cstdint>
#include <cstddef>

// ---------------------------------------------------------------------------
// GCNemb: 8-layer GCN. N=100000, E=3200000.
//   - CSR by target; agg(xW)==agg(x)W -> aggregate on smaller side.
//   - bf16 activation storage, fp32 arithmetic (r2: costs 1.5e-5 absmax;
//     r3 with bf16 MFMA: 4.6e-5 vs 6.56e-5 threshold -> no more precision cuts).
//   - r4: latency-oriented gathers: edge-batched shfl-broadcast + 4-wide
//     unrolled gathers; wave-per-node small aggs; fused L0; wave-dot L7.
// ---------------------------------------------------------------------------

#define TPB 256

typedef short short8 __attribute__((ext_vector_type(8)));
typedef float f32x4 __attribute__((ext_vector_type(4)));

__device__ __forceinline__ float b2f(unsigned short u) {
    union { unsigned int i; float f; } c; c.i = ((unsigned int)u) << 16; return c.f;
}
__device__ __forceinline__ unsigned short f2b(float f) {
    __hip_bfloat16 h = __float2bfloat16(f);
    union { __hip_bfloat16 h; unsigned short u; } c; c.h = h; return c.u;
}

__device__ __forceinline__ void async_copy16(void* lds, const void* g) {
    __builtin_amdgcn_global_load_lds(
        (const __attribute__((address_space(1))) void*)g,
        (__attribute__((address_space(3))) void*)lds,
        16, 0, 0);
}

// ------------------------------ graph prep --------------------------------

__global__ void count_deg_kernel(const int* __restrict__ col, int* __restrict__ deg,
                                 int E, int n) {
    int e = blockIdx.x * blockDim.x + threadIdx.x;
    if (e < E) {
        int c = col[e];
        if ((unsigned)c < (unsigned)n) atomicAdd(&deg[c], 1);
    }
}

__global__ void dinv_kernel(const int* __restrict__ deg, float* __restrict__ dinv, int n) {
    int i = blockIdx.x * blockDim.x + threadIdx.x;
    if (i < n) dinv[i] = 1.0f / sqrtf((float)(deg[i] + 1));  // +1 self-loop
}

__global__ void scan_kernel(const int* __restrict__ deg, int* __restrict__ rowptr,
                            int* __restrict__ cursor, int n) {
    __shared__ int sums[1024];
    int tid = threadIdx.x;
    int chunk = (n + 1023) >> 10;
    int lo = tid * chunk;
    int hi = lo + chunk; if (hi > n) hi = n;
    int s = 0;
    for (int i = lo; i < hi; i++) s += deg[i];
    sums[tid] = s;
    __syncthreads();
    for (int off = 1; off < 1024; off <<= 1) {
        int v = (tid >= off) ? sums[tid - off] : 0;
        __syncthreads();
        sums[tid] += v;
        __syncthreads();
    }
    int run = (tid == 0) ? 0 : sums[tid - 1];
    for (int i = lo; i < hi; i++) {
        rowptr[i] = run; cursor[i] = run;
        run += deg[i];
    }
    if (tid == 1023) rowptr[n] = sums[1023];
}

__global__ void fill_csr_kernel(const int* __restrict__ row, const int* __restrict__ col,
                                int* __restrict__ cursor, int* __restrict__ srcs,
                                int E, int n) {
    int e = blockIdx.x * blockDim.x + threadIdx.x;
    if (e < E) {
        int c = col[e];
        if ((unsigned)c < (unsigned)n) {
            int pos = atomicAdd(&cursor[c], 1);
            if ((unsigned)pos < (unsigned)E) srcs[pos] = row[e];
        }
    }
}

// weight prep: W[K x M] fp32 -> Wt[M x K] bf16
__global__ void convert_wt_kernel(const float* __restrict__ W, unsigned short* __restrict__ Wt,
                                  int K, int M) {
    int idx = blockIdx.x * blockDim.x + threadIdx.x;
    if (idx < K * M) {
        int k = idx / M, m = idx % M;
        Wt[(size_t)m * K + k] = f2b(W[idx]);
    }
}

// ----------------------------- aggregation --------------------------------

template <int VEC> struct Pack;
template <> struct Pack<1> { using T = unsigned short; };
template <> struct Pack<2> { using T = unsigned int; };
template <> struct Pack<4> { using T = uint2; };
template <> struct Pack<8> { using T = uint4; };

// One wave per node; lane owns VEC contiguous bf16 features. width = 64*VEC.
// Edge indices batch-loaded (64 per coalesced read), broadcast via shfl,
// gathers unrolled 4-wide into independent accumulators.
template <int VEC>
__global__ __launch_bounds__(TPB) void agg_bf16_kernel(
        const unsigned short* __restrict__ x, unsigned short* __restrict__ out,
        const int* __restrict__ rowptr, const int* __restrict__ srcs,
        const float* __restrict__ dinv, const float* __restrict__ bias,
        int n, int relu) {
    using P = typename Pack<VEC>::T;
    const int d = 64 * VEC;
    int wid  = (blockIdx.x * blockDim.x + threadIdx.x) >> 6;
    int lane = threadIdx.x & 63;
    if (wid >= n) return;
    int start = rowptr[wid], end = rowptr[wid + 1];
    float acc0[VEC], acc1[VEC], acc2[VEC], acc3[VEC];
#pragma unroll
    for (int j = 0; j < VEC; j++) { acc0[j] = 0.f; acc1[j] = 0.f; acc2[j] = 0.f; acc3[j] = 0.f; }
    const int fo = lane * VEC;
    union U { P v; unsigned short u[VEC]; };

    for (int base = start; base < end; base += 64) {
        int idx = base + lane;
        int clamped = (idx < end) ? idx : (end - 1);
        int sv = srcs[clamped];
        float dv = 0.f;
        if (idx < end) dv = dinv[sv];
        int cnt = end - base; if (cnt > 64) cnt = 64;
        int j = 0;
        for (; j + 4 <= cnt; j += 4) {
            int   s0 = __shfl(sv, j),     s1 = __shfl(sv, j + 1);
            int   s2 = __shfl(sv, j + 2), s3 = __shfl(sv, j + 3);
            float e0 = __shfl(dv, j),     e1 = __shfl(dv, j + 1);
            float e2 = __shfl(dv, j + 2), e3 = __shfl(dv, j + 3);
            U l0, l1, l2, l3;
            l0.v = *(const P*)(x + (size_t)s0 * d + fo);
            l1.v = *(const P*)(x + (size_t)s1 * d + fo);
            l2.v = *(const P*)(x + (size_t)s2 * d + fo);
            l3.v = *(const P*)(x + (size_t)s3 * d + fo);
#pragma unroll
            for (int q = 0; q < VEC; q++) {
                acc0[q] = fmaf(e0, b2f(l0.u[q]), acc0[q]);
                acc1[q] = fmaf(e1, b2f(l1.u[q]), acc1[q]);
                acc2[q] = fmaf(e2, b2f(l2.u[q]), acc2[q]);
                acc3[q] = fmaf(e3, b2f(l3.u[q]), acc3[q]);
            }
        }
        for (; j < cnt; j++) {
            int   s0 = __shfl(sv, j);
            float e0 = __shfl(dv, j);
            U l0; l0.v = *(const P*)(x + (size_t)s0 * d + fo);
#pragma unroll
            for (int q = 0; q < VEC; q++) acc0[q] = fmaf(e0, b2f(l0.u[q]), acc0[q]);
        }
    }

    float di = dinv[wid];
    U ls; ls.v = *(const P*)(x + (size_t)wid * d + fo);
    U st;
#pragma unroll
    for (int j = 0; j < VEC; j++) {
        float a = (acc0[j] + acc1[j]) + (acc2[j] + acc3[j]);
        float v = di * (a + di * b2f(ls.u[j]));
        if (bias) v += bias[fo + j];
        if (relu) v = fmaxf(v, 0.f);
        st.u[j] = f2b(v);
    }
    *(P*)(out + (size_t)wid * d + fo) = st.v;
}

// Wave-per-node, edge-parallel aggregation for tiny dims (fp32 x), with
// optional fused (D -> 64) GEMM + bias + relu -> bf16 output (L0 path).
template <int D, int FUSE64>
__global__ __launch_bounds__(TPB) void agg_small_wave_kernel(
        const float* __restrict__ x, float* __restrict__ outf,
        unsigned short* __restrict__ outb,
        const int* __restrict__ rowptr, const int* __restrict__ srcs,
        const float* __restrict__ dinv, const float* __restrict__ bias,
        const float* __restrict__ W, int n, int relu) {
    int wid  = (blockIdx.x * blockDim.x + threadIdx.x) >> 6;
    int lane = threadIdx.x & 63;
    if (wid >= n) return;
    int start = rowptr[wid], end = rowptr[wid + 1];
    float acc[D];
#pragma unroll
    for (int j = 0; j < D; j++) acc[j] = 0.f;
    for (int e = start + lane; e < end; e += 64) {
        int s = srcs[e];
        float ds = dinv[s];
#pragma unroll
        for (int j = 0; j < D; j++) acc[j] = fmaf(ds, x[(size_t)s * D + j], acc[j]);
    }
    // butterfly reduce each component across the wave
#pragma unroll
    for (int j = 0; j < D; j++) {
#pragma unroll
        for (int off = 32; off >= 1; off >>= 1) acc[j] += __shfl_xor(acc[j], off);
    }
    float di = dinv[wid];
    float aggv[D];
#pragma unroll
    for (int j = 0; j < D; j++) aggv[j] = di * (acc[j] + di * x[(size_t)wid * D + j]);

    if (FUSE64) {
        // out[wid,lane] = relu(bias[lane] + sum_j aggv[j] * W[j*64+lane])
        float v = bias[lane];
#pragma unroll
        for (int j = 0; j < D; j++) v = fmaf(aggv[j], W[j * 64 + lane], v);
        v = fmaxf(v, 0.f);
        outb[(size_t)wid * 64 + lane] = f2b(v);
    } else {
        if (lane < D) {
            float v = aggv[lane];
            if (bias) v += bias[lane];
            if (relu) v = fmaxf(v, 0.f);
            outf[(size_t)wid * D + lane] = v;
        }
    }
}

// Wave-per-node GEMM for L7: pre[n x 2] = A[n x 256](bf16) @ W[256 x 2](fp32)
__global__ __launch_bounds__(TPB) void gemm_dot2_kernel(
        const unsigned short* __restrict__ A, const float* __restrict__ W,
        float* __restrict__ pre, int n) {
    int wid  = (blockIdx.x * blockDim.x + threadIdx.x) >> 6;
    int lane = threadIdx.x & 63;
    if (wid >= n) return;
    union { uint2 v; unsigned short u[4]; } a;
    a.v = *(const uint2*)(A + (size_t)wid * 256 + lane * 4);
    float c0 = 0.f, c1 = 0.f;
#pragma unroll
    for (int j = 0; j < 4; j++) {
        float av = b2f(a.u[j]);
        c0 = fmaf(av, W[(lane * 4 + j) * 2 + 0], c0);
        c1 = fmaf(av, W[(lane * 4 + j) * 2 + 1], c1);
    }
#pragma unroll
    for (int off = 32; off >= 1; off >>= 1) {
        c0 += __shfl_xor(c0, off);
        c1 += __shfl_xor(c1, off);
    }
    if (lane == 0) { pre[(size_t)wid * 2 + 0] = c0; pre[(size_t)wid * 2 + 1] = c1; }
}

// ------------------------------ VALU GEMM ---------------------------------
__device__ inline float to_f(float v) { return v; }
__device__ inline float to_f(__hip_bfloat16 v) { return __bfloat162float(v); }
__device__ inline void from_f(float v, float& d) { d = v; }
__device__ inline void from_f(float v, __hip_bfloat16& d) { d = __float2bfloat16(v); }

#define BM 64
#define BN 64
#define BK 16
template <typename TA, typename TC>
__global__ __launch_bounds__(256) void gemm_valu_kernel(
        const TA* __restrict__ A, const float* __restrict__ W,
        const float* __restrict__ bias, TC* __restrict__ C,
        int nr, int K, int M, int relu, int addbias) {
    __shared__ float As[BK][BM + 4];
    __shared__ float Bs[BK][BN + 4];
    int tid  = threadIdx.x;
    int row0 = blockIdx.x * BM;
    int col0 = blockIdx.y * BN;
    int rm = (tid >> 4) << 2;
    int rn = (tid & 15) << 2;
    float acc[4][4];
#pragma unroll
    for (int y = 0; y < 4; y++)
#pragma unroll
        for (int xj = 0; xj < 4; xj++) acc[y][xj] = 0.f;

    for (int kk = 0; kk < K; kk += BK) {
#pragma unroll
        for (int i = 0; i < 4; i++) {
            int idx = tid + i * 256;
            int k = idx & 15, r = idx >> 4;
            int gr = row0 + r, gk = kk + k;
            float v = 0.f;
            if (gr < nr && gk < K) v = to_f(A[(size_t)gr * K + gk]);
            As[k][r] = v;
        }
#pragma unroll
        for (int i = 0; i < 4; i++) {
            int idx = tid + i * 256;
            int k = idx >> 6, c = idx & 63;
            int gk = kk + k, gc = col0 + c;
            float v = 0.f;
            if (gk < K && gc < M) v = W[(size_t)gk * M + gc];
            Bs[k][c] = v;
        }
        __syncthreads();
#pragma unroll
        for (int k = 0; k < BK; k++) {
            float a[4], b[4];
#pragma unroll
            for (int j = 0; j < 4; j++) { a[j] = As[k][rm + j]; b[j] = Bs[k][rn + j]; }
#pragma unroll
            for (int y = 0; y < 4; y++)
#pragma unroll
                for (int xj = 0; xj < 4; xj++)
                    acc[y][xj] = fmaf(a[y], b[xj], acc[y][xj]);
        }
        __syncthreads();
    }
#pragma unroll
    for (int y = 0; y < 4; y++) {
        int gr = row0 + rm + y;
        if (gr >= nr) continue;
#pragma unroll
        for (int xj = 0; xj < 4; xj++) {
            int gc = col0 + rn + xj;
            if (gc >= M) continue;
            float v = acc[y][xj];
            if (addbias) v += bias[gc];
            if (relu) v = fmaxf(v, 0.f);
            from_f(v, C[(size_t)gr * M + gc]);
        }
    }
}

template <typename TA, typename TC>
static inline void launch_gemm_valu(const TA* A, const float* W, const float* bias,
                                    TC* C, int nr, int K, int M, int relu, int addbias,
                                    hipStream_t stream) {
    dim3 grid((nr + BM - 1) / BM, (M + BN - 1) / BN);
    gemm_valu_kernel<TA, TC><<<grid, 256, 0, stream>>>(A, W, bias, C, nr, K, M, relu, addbias);
}

// ------------------------------ MFMA GEMM ---------------------------------
// C[nr x M] = A[nr x K](bf16) * Wt[M x K](bf16, pre-transposed) (+bias)(+relu)
// 128x128 tile, BK=32, 2x2 waves x 4x4 frags of v_mfma_f32_16x16x32_bf16.
__global__ __launch_bounds__(256) void gemm_mfma_kernel(
        const unsigned short* __restrict__ A, const unsigned short* __restrict__ Wt,
        const float* __restrict__ bias, unsigned short* __restrict__ C,
        int nr, int K, int M, int relu, int addbias) {
    __shared__ alignas(16) short As[128 * 32];
    __shared__ alignas(16) short Bs[128 * 32];
    const int tid  = threadIdx.x;
    const int w    = tid >> 6;
    const int lane = tid & 63;
    const int wr   = w >> 1;
    const int wc   = w & 1;
    const int row0 = blockIdx.x * 128;
    const int col0 = blockIdx.y * 128;

    f32x4 acc[4][4];
#pragma unroll
    for (int i = 0; i < 4; i++)
#pragma unroll
        for (int j = 0; j < 4; j++) acc[i][j] = {0.f, 0.f, 0.f, 0.f};

    const int lrow   = lane >> 2;
    const int lcolB  = (lane & 3) * 16;
    const int fm     = lane & 15;
    const int fq     = lane >> 4;

    for (int kk = 0; kk < K; kk += 32) {
#pragma unroll
        for (int i = 0; i < 2; i++) {
            int r = w * 32 + i * 16 + lrow;
            int grow = row0 + r;
            const char* g = (const char*)A + ((size_t)grow * K + kk) * 2 + lcolB;
            short* lds = &As[(w * 32 + i * 16) * 32];
            if (grow < nr) async_copy16(lds, g);
        }
#pragma unroll
        for (int i = 0; i < 2; i++) {
            int r = w * 32 + i * 16 + lrow;
            int gcol = col0 + r;
            const char* g = (const char*)Wt + ((size_t)gcol * K + kk) * 2 + lcolB;
            short* lds = &Bs[(w * 32 + i * 16) * 32];
            async_copy16(lds, g);
        }
        __syncthreads();

        short8 a[4], b[4];
#pragma unroll
        for (int i = 0; i < 4; i++) {
            a[i] = *(const short8*)&As[(wr * 64 + i * 16 + fm) * 32 + fq * 8];
            b[i] = *(const short8*)&Bs[(wc * 64 + i * 16 + fm) * 32 + fq * 8];
        }
#pragma unroll
        for (int mi = 0; mi < 4; mi++)
#pragma unroll
            for (int ni = 0; ni < 4; ni++)
                acc[mi][ni] = __builtin_amdgcn_mfma_f32_16x16x32_bf16(
                    a[mi], b[ni], acc[mi][ni], 0, 0, 0);
        __syncthreads();
    }

#pragma unroll
    for (int mi = 0; mi < 4; mi++) {
#pragma unroll
        for (int r = 0; r < 4; r++) {
            int row = row0 + wr * 64 + mi * 16 + fq * 4 + r;
            if (row >= nr) continue;
            size_t rb = (size_t)row * M;
#pragma unroll
            for (int ni = 0; ni < 4; ni++) {
                int col = col0 + wc * 64 + ni * 16 + fm;
                float v = acc[mi][ni][r];
                if (addbias) v += bias[col];
                if (relu) v = fmaxf(v, 0.f);
                C[rb + col] = f2b(v);
            }
        }
    }
}

static inline void launch_gemm_mfma(const unsigned short* A, const unsigned short* Wt,
                                    const float* bias, unsigned short* C,
                                    int nr, int K, int M, int relu, int addbias,
                                    hipStream_t stream) {
    dim3 grid((nr + 127) / 128, M / 128);
    gemm_mfma_kernel<<<grid, 256, 0, stream>>>(A, Wt, bias, C, nr, K, M, relu, addbias);
}

// ------------------------------- driver -----------------------------------

static inline size_t al256(size_t x) { return (x + 255) & ~(size_t)255; }

extern "C" void kernel_launch(void* const* d_in, const int* in_sizes, int n_in,
                              void* d_out, int out_size, void* d_ws, size_t ws_size,
                              hipStream_t stream) {
    const float* x  = (const float*)d_in[0];
    const int*   ei = (const int*)d_in[1];
    const int E = in_sizes[1] / 2;
    const int n = in_sizes[0] / 3;
    const int* rowv = ei;        // sources
    const int* colv = ei + E;    // targets

    const float* Wf[8]; const float* bt[8];
    for (int i = 0; i < 8; i++) { Wf[i] = (const float*)d_in[2 + 2 * i]; bt[i] = (const float*)d_in[3 + 2 * i]; }

    char* p = (char*)d_ws;
    size_t used = 0;
    auto carve = [&](size_t bytes) -> char* {
        char* r = p + used; used += al256(bytes); return r;
    };
    int*   deg    = (int*)carve((size_t)n * 4);
    float* dinv   = (float*)carve((size_t)n * 4);
    int*   rowptr = (int*)carve((size_t)(n + 1) * 4);
    int*   cursor = (int*)carve((size_t)(n + 1) * 4);
    int*   srcs   = (int*)carve((size_t)E * 4);
    unsigned short* bufA = (unsigned short*)carve((size_t)n * 512 * 2);
    unsigned short* bufB = (unsigned short*)carve((size_t)n * 512 * 2);
    const size_t wt3e = 64 * 128, wt4e = 128 * 1024, wt5e = 1024 * 512, wt6e = 512 * 256;
    unsigned short* wt3 = (unsigned short*)carve((wt3e + wt4e + wt5e + wt6e) * 2);
    unsigned short* wt4 = wt3 + wt3e;
    unsigned short* wt5 = wt4 + wt4e;
    unsigned short* wt6 = wt5 + wt5e;
    size_t avail = (ws_size > used) ? (ws_size - used) : 0;
    int chunk = (int)(avail / (1024 * 2));
    if (chunk > n) chunk = n;
    chunk &= ~127;                  // multiple of 128 for clean MFMA tiles
    if (chunk < 2048) chunk = 2048; // floor (ws >= 246MB guarantees fit)
    char* tmp_raw = carve((size_t)chunk * 1024 * 2);
    unsigned short* tmpb = (unsigned short*)tmp_raw;
    float* tmpf = (float*)tmp_raw;   // reused: n x 2 fp32 (L7 pre-agg)

    const int EB = (E + TPB - 1) / TPB;
    const int NB = (n + TPB - 1) / TPB;
    const int NW = (n + 3) / 4;  // wave-per-node kernels, 4 waves/block

    // ---- graph preprocessing ----
    hipMemsetAsync(deg, 0, (size_t)n * 4, stream);
    count_deg_kernel<<<EB, TPB, 0, stream>>>(colv, deg, E, n);
    dinv_kernel<<<NB, TPB, 0, stream>>>(deg, dinv, n);
    scan_kernel<<<1, 1024, 0, stream>>>(deg, rowptr, cursor, n);
    fill_csr_kernel<<<EB, TPB, 0, stream>>>(rowv, colv, cursor, srcs, E, n);

    // ---- weight prep ----
    convert_wt_kernel<<<(int)((wt3e + 255) / 256), 256, 0, stream>>>(Wf[3], wt3, 64, 128);
    convert_wt_kernel<<<(int)((wt4e + 255) / 256), 256, 0, stream>>>(Wf[4], wt4, 128, 1024);
    convert_wt_kernel<<<(int)((wt5e + 255) / 256), 256, 0, stream>>>(Wf[5], wt5, 1024, 512);
    convert_wt_kernel<<<(int)((wt6e + 255) / 256), 256, 0, stream>>>(Wf[6], wt6, 512, 256);

    // ---- L0: fused agg(d=3) + (3->64 GEMM) + bias + relu -> bf16 ----
    agg_small_wave_kernel<3, 1><<<NW, TPB, 0, stream>>>(
        x, nullptr, bufA, rowptr, srcs, dinv, bt[0], Wf[0], n, 1);

    // ---- L1, L2: 64 -> 64 (agg-first, VALU gemm) ----
    agg_bf16_kernel<1><<<NW, TPB, 0, stream>>>(bufA, bufB, rowptr, srcs, dinv, nullptr, n, 0);
    launch_gemm_valu<__hip_bfloat16, __hip_bfloat16>((const __hip_bfloat16*)bufB, Wf[1], bt[1],
                                                     (__hip_bfloat16*)bufA, n, 64, 64, 1, 1, stream);
    agg_bf16_kernel<1><<<NW, TPB, 0, stream>>>(bufA, bufB, rowptr, srcs, dinv, nullptr, n, 0);
    launch_gemm_valu<__hip_bfloat16, __hip_bfloat16>((const __hip_bfloat16*)bufB, Wf[2], bt[2],
                                                     (__hip_bfloat16*)bufA, n, 64, 64, 1, 1, stream);

    // ---- L3: 64 -> 128 (agg-first, MFMA) ----
    agg_bf16_kernel<1><<<NW, TPB, 0, stream>>>(bufA, bufB, rowptr, srcs, dinv, nullptr, n, 0);
    launch_gemm_mfma(bufB, wt3, bt[3], bufA, n, 64, 128, 1, 1, stream);

    // ---- L4+L5 fused: agg on 128, then chunked (relu(.@W4+b4)) @ W5 ----
    agg_bf16_kernel<2><<<NW, TPB, 0, stream>>>(bufA, bufB, rowptr, srcs, dinv, nullptr, n, 0);
    for (int r0 = 0; r0 < n; r0 += chunk) {
        int ch = n - r0; if (ch > chunk) ch = chunk;
        launch_gemm_mfma(bufB + (size_t)r0 * 128, wt4, bt[4], tmpb, ch, 128, 1024, 1, 1, stream);
        launch_gemm_mfma(tmpb, wt5, nullptr, bufA + (size_t)r0 * 512, ch, 1024, 512, 0, 0, stream);
    }
    // L5 epilogue: agg on 512, bias5 + relu
    agg_bf16_kernel<8><<<NW, TPB, 0, stream>>>(bufA, bufB, rowptr, srcs, dinv, bt[5], n, 1);

    // ---- L6: 512 -> 256 (matmul-first MFMA, agg on 256) ----
    launch_gemm_mfma(bufB, wt6, nullptr, bufA, n, 512, 256, 0, 0, stream);
    agg_bf16_kernel<4><<<NW, TPB, 0, stream>>>(bufA, bufB, rowptr, srcs, dinv, bt[6], n, 1);

    // ---- L7: wave-dot GEMM (256->2), then agg d=2 + bias, no relu ----
    gemm_dot2_kernel<<<NW, TPB, 0, stream>>>(bufB, Wf[7], tmpf, n);
    agg_small_wave_kernel<2, 0><<<NW, TPB, 0, stream>>>(
        tmpf, (float*)d_out, nullptr, rowptr, srcs, dinv, bt[7], nullptr, n, 0);
}

// Round 5
// 2220.785 us; speedup vs baseline: 2.9761x; 1.0567x over previous
//
#include <hip/hip_runtime.h>
#include <hip/hip_bf16.h>
#include <cstdint>
#include <cstddef>

// ---------------------------------------------------------------------------
// GCNemb: 8-layer GCN. N=100000, E=3200000.
//   - CSR by target; agg(xW)==agg(x)W -> aggregate on smaller side.
//   - bf16 activation storage, fp32 arithmetic (absmax 4.6e-5 vs 6.56e-5 thr).
//   - r5: feature-window tiling (<=256 cols/pass) so gather working set fits
//     L3 (r4 showed 1.7GB HBM fetch on a 102MB table = L3 thrash at width 512);
//     (src,dinv) packed per-edge int2 kills the dependent dinv gather.
// ---------------------------------------------------------------------------

#define TPB 256

typedef short short8 __attribute__((ext_vector_type(8)));
typedef float f32x4 __attribute__((ext_vector_type(4)));

__device__ __forceinline__ float b2f(unsigned short u) {
    union { unsigned int i; float f; } c; c.i = ((unsigned int)u) << 16; return c.f;
}
__device__ __forceinline__ unsigned short f2b(float f) {
    __hip_bfloat16 h = __float2bfloat16(f);
    union { __hip_bfloat16 h; unsigned short u; } c; c.h = h; return c.u;
}

__device__ __forceinline__ void async_copy16(void* lds, const void* g) {
    __builtin_amdgcn_global_load_lds(
        (const __attribute__((address_space(1))) void*)g,
        (__attribute__((address_space(3))) void*)lds,
        16, 0, 0);
}

// ------------------------------ graph prep --------------------------------

__global__ void count_deg_kernel(const int* __restrict__ col, int* __restrict__ deg,
                                 int E, int n) {
    int e = blockIdx.x * blockDim.x + threadIdx.x;
    if (e < E) {
        int c = col[e];
        if ((unsigned)c < (unsigned)n) atomicAdd(&deg[c], 1);
    }
}

__global__ void dinv_kernel(const int* __restrict__ deg, float* __restrict__ dinv, int n) {
    int i = blockIdx.x * blockDim.x + threadIdx.x;
    if (i < n) dinv[i] = 1.0f / sqrtf((float)(deg[i] + 1));  // +1 self-loop
}

__global__ void scan_kernel(const int* __restrict__ deg, int* __restrict__ rowptr,
                            int* __restrict__ cursor, int n) {
    __shared__ int sums[1024];
    int tid = threadIdx.x;
    int chunk = (n + 1023) >> 10;
    int lo = tid * chunk;
    int hi = lo + chunk; if (hi > n) hi = n;
    int s = 0;
    for (int i = lo; i < hi; i++) s += deg[i];
    sums[tid] = s;
    __syncthreads();
    for (int off = 1; off < 1024; off <<= 1) {
        int v = (tid >= off) ? sums[tid - off] : 0;
        __syncthreads();
        sums[tid] += v;
        __syncthreads();
    }
    int run = (tid == 0) ? 0 : sums[tid - 1];
    for (int i = lo; i < hi; i++) {
        rowptr[i] = run; cursor[i] = run;
        run += deg[i];
    }
    if (tid == 1023) rowptr[n] = sums[1023];
}

// fill CSR with packed (src, dinv[src]) per edge
__global__ void fill_csr_kernel(const int* __restrict__ row, const int* __restrict__ col,
                                const float* __restrict__ dinv,
                                int* __restrict__ cursor, int2* __restrict__ es,
                                int E, int n) {
    int e = blockIdx.x * blockDim.x + threadIdx.x;
    if (e < E) {
        int c = col[e];
        if ((unsigned)c < (unsigned)n) {
            int r = row[e];
            int pos = atomicAdd(&cursor[c], 1);
            if ((unsigned)pos < (unsigned)E) {
                es[pos] = make_int2(r, __float_as_int(dinv[r]));
            }
        }
    }
}

// weight prep: W[K x M] fp32 -> Wt[M x K] bf16
__global__ void convert_wt_kernel(const float* __restrict__ W, unsigned short* __restrict__ Wt,
                                  int K, int M) {
    int idx = blockIdx.x * blockDim.x + threadIdx.x;
    if (idx < K * M) {
        int k = idx / M, m = idx % M;
        Wt[(size_t)m * K + k] = f2b(W[idx]);
    }
}

// ----------------------------- aggregation --------------------------------

template <int VEC> struct Pack;
template <> struct Pack<1> { using T = unsigned short; };
template <> struct Pack<2> { using T = unsigned int; };
template <> struct Pack<4> { using T = uint2; };

// One wave per node; lane owns VEC contiguous bf16 features inside a column
// window starting at wb; full row stride is d. Edge (src,dinv) batch-loaded
// 64-at-a-time (8B coalesced), broadcast via shfl, gathers unrolled 4-wide.
template <int VEC>
__global__ __launch_bounds__(TPB) void agg_win_kernel(
        const unsigned short* __restrict__ x, unsigned short* __restrict__ out,
        const int* __restrict__ rowptr, const int2* __restrict__ es,
        const float* __restrict__ dinv, const float* __restrict__ bias,
        int n, int d, int wb, int relu) {
    using P = typename Pack<VEC>::T;
    int wid  = (blockIdx.x * blockDim.x + threadIdx.x) >> 6;
    int lane = threadIdx.x & 63;
    if (wid >= n) return;
    int start = rowptr[wid], end = rowptr[wid + 1];
    float acc0[VEC], acc1[VEC], acc2[VEC], acc3[VEC];
#pragma unroll
    for (int j = 0; j < VEC; j++) { acc0[j] = 0.f; acc1[j] = 0.f; acc2[j] = 0.f; acc3[j] = 0.f; }
    const int fo = wb + lane * VEC;
    union U { P v; unsigned short u[VEC]; };

    for (int base = start; base < end; base += 64) {
        int idx = base + lane;
        int clamped = (idx < end) ? idx : (end - 1);
        int2 ev = es[clamped];
        int   sv = ev.x;
        float dv = (idx < end) ? __int_as_float(ev.y) : 0.f;
        int cnt = end - base; if (cnt > 64) cnt = 64;
        int j = 0;
        for (; j + 4 <= cnt; j += 4) {
            int   s0 = __shfl(sv, j),     s1 = __shfl(sv, j + 1);
            int   s2 = __shfl(sv, j + 2), s3 = __shfl(sv, j + 3);
            float e0 = __shfl(dv, j),     e1 = __shfl(dv, j + 1);
            float e2 = __shfl(dv, j + 2), e3 = __shfl(dv, j + 3);
            U l0, l1, l2, l3;
            l0.v = *(const P*)(x + (size_t)s0 * d + fo);
            l1.v = *(const P*)(x + (size_t)s1 * d + fo);
            l2.v = *(const P*)(x + (size_t)s2 * d + fo);
            l3.v = *(const P*)(x + (size_t)s3 * d + fo);
#pragma unroll
            for (int q = 0; q < VEC; q++) {
                acc0[q] = fmaf(e0, b2f(l0.u[q]), acc0[q]);
                acc1[q] = fmaf(e1, b2f(l1.u[q]), acc1[q]);
                acc2[q] = fmaf(e2, b2f(l2.u[q]), acc2[q]);
                acc3[q] = fmaf(e3, b2f(l3.u[q]), acc3[q]);
            }
        }
        for (; j < cnt; j++) {
            int   s0 = __shfl(sv, j);
            float e0 = __shfl(dv, j);
            U l0; l0.v = *(const P*)(x + (size_t)s0 * d + fo);
#pragma unroll
            for (int q = 0; q < VEC; q++) acc0[q] = fmaf(e0, b2f(l0.u[q]), acc0[q]);
        }
    }

    float di = dinv[wid];
    U ls; ls.v = *(const P*)(x + (size_t)wid * d + fo);
    U st;
#pragma unroll
    for (int j = 0; j < VEC; j++) {
        float a = (acc0[j] + acc1[j]) + (acc2[j] + acc3[j]);
        float v = di * (a + di * b2f(ls.u[j]));
        if (bias) v += bias[fo + j];
        if (relu) v = fmaxf(v, 0.f);
        st.u[j] = f2b(v);
    }
    *(P*)(out + (size_t)wid * d + fo) = st.v;
}

// Wave-per-node, edge-parallel aggregation for tiny dims (fp32 x), with
// optional fused (D -> 64) GEMM + bias + relu -> bf16 output (L0 path).
template <int D, int FUSE64>
__global__ __launch_bounds__(TPB) void agg_small_wave_kernel(
        const float* __restrict__ x, float* __restrict__ outf,
        unsigned short* __restrict__ outb,
        const int* __restrict__ rowptr, const int2* __restrict__ es,
        const float* __restrict__ dinv, const float* __restrict__ bias,
        const float* __restrict__ W, int n, int relu) {
    int wid  = (blockIdx.x * blockDim.x + threadIdx.x) >> 6;
    int lane = threadIdx.x & 63;
    if (wid >= n) return;
    int start = rowptr[wid], end = rowptr[wid + 1];
    float acc[D];
#pragma unroll
    for (int j = 0; j < D; j++) acc[j] = 0.f;
    for (int e = start + lane; e < end; e += 64) {
        int2 ev = es[e];
        int s = ev.x;
        float ds = __int_as_float(ev.y);
#pragma unroll
        for (int j = 0; j < D; j++) acc[j] = fmaf(ds, x[(size_t)s * D + j], acc[j]);
    }
#pragma unroll
    for (int j = 0; j < D; j++) {
#pragma unroll
        for (int off = 32; off >= 1; off >>= 1) acc[j] += __shfl_xor(acc[j], off);
    }
    float di = dinv[wid];
    float aggv[D];
#pragma unroll
    for (int j = 0; j < D; j++) aggv[j] = di * (acc[j] + di * x[(size_t)wid * D + j]);

    if (FUSE64) {
        float v = bias[lane];
#pragma unroll
        for (int j = 0; j < D; j++) v = fmaf(aggv[j], W[j * 64 + lane], v);
        v = fmaxf(v, 0.f);
        outb[(size_t)wid * 64 + lane] = f2b(v);
    } else {
        if (lane < D) {
            float v = aggv[lane];
            if (bias) v += bias[lane];
            if (relu) v = fmaxf(v, 0.f);
            outf[(size_t)wid * D + lane] = v;
        }
    }
}

// Wave-per-node GEMM for L7: pre[n x 2] = A[n x 256](bf16) @ W[256 x 2](fp32)
__global__ __launch_bounds__(TPB) void gemm_dot2_kernel(
        const unsigned short* __restrict__ A, const float* __restrict__ W,
        float* __restrict__ pre, int n) {
    int wid  = (blockIdx.x * blockDim.x + threadIdx.x) >> 6;
    int lane = threadIdx.x & 63;
    if (wid >= n) return;
    union { uint2 v; unsigned short u[4]; } a;
    a.v = *(const uint2*)(A + (size_t)wid * 256 + lane * 4);
    float c0 = 0.f, c1 = 0.f;
#pragma unroll
    for (int j = 0; j < 4; j++) {
        float av = b2f(a.u[j]);
        c0 = fmaf(av, W[(lane * 4 + j) * 2 + 0], c0);
        c1 = fmaf(av, W[(lane * 4 + j) * 2 + 1], c1);
    }
#pragma unroll
    for (int off = 32; off >= 1; off >>= 1) {
        c0 += __shfl_xor(c0, off);
        c1 += __shfl_xor(c1, off);
    }
    if (lane == 0) { pre[(size_t)wid * 2 + 0] = c0; pre[(size_t)wid * 2 + 1] = c1; }
}

// ------------------------------ VALU GEMM ---------------------------------
__device__ inline float to_f(float v) { return v; }
__device__ inline float to_f(__hip_bfloat16 v) { return __bfloat162float(v); }
__device__ inline void from_f(float v, float& d) { d = v; }
__device__ inline void from_f(float v, __hip_bfloat16& d) { d = __float2bfloat16(v); }

#define BM 64
#define BN 64
#define BK 16
template <typename TA, typename TC>
__global__ __launch_bounds__(256) void gemm_valu_kernel(
        const TA* __restrict__ A, const float* __restrict__ W,
        const float* __restrict__ bias, TC* __restrict__ C,
        int nr, int K, int M, int relu, int addbias) {
    __shared__ float As[BK][BM + 4];
    __shared__ float Bs[BK][BN + 4];
    int tid  = threadIdx.x;
    int row0 = blockIdx.x * BM;
    int col0 = blockIdx.y * BN;
    int rm = (tid >> 4) << 2;
    int rn = (tid & 15) << 2;
    float acc[4][4];
#pragma unroll
    for (int y = 0; y < 4; y++)
#pragma unroll
        for (int xj = 0; xj < 4; xj++) acc[y][xj] = 0.f;

    for (int kk = 0; kk < K; kk += BK) {
#pragma unroll
        for (int i = 0; i < 4; i++) {
            int idx = tid + i * 256;
            int k = idx & 15, r = idx >> 4;
            int gr = row0 + r, gk = kk + k;
            float v = 0.f;
            if (gr < nr && gk < K) v = to_f(A[(size_t)gr * K + gk]);
            As[k][r] = v;
        }
#pragma unroll
        for (int i = 0; i < 4; i++) {
            int idx = tid + i * 256;
            int k = idx >> 6, c = idx & 63;
            int gk = kk + k, gc = col0 + c;
            float v = 0.f;
            if (gk < K && gc < M) v = W[(size_t)gk * M + gc];
            Bs[k][c] = v;
        }
        __syncthreads();
#pragma unroll
        for (int k = 0; k < BK; k++) {
            float a[4], b[4];
#pragma unroll
            for (int j = 0; j < 4; j++) { a[j] = As[k][rm + j]; b[j] = Bs[k][rn + j]; }
#pragma unroll
            for (int y = 0; y < 4; y++)
#pragma unroll
                for (int xj = 0; xj < 4; xj++)
                    acc[y][xj] = fmaf(a[y], b[xj], acc[y][xj]);
        }
        __syncthreads();
    }
#pragma unroll
    for (int y = 0; y < 4; y++) {
        int gr = row0 + rm + y;
        if (gr >= nr) continue;
#pragma unroll
        for (int xj = 0; xj < 4; xj++) {
            int gc = col0 + rn + xj;
            if (gc >= M) continue;
            float v = acc[y][xj];
            if (addbias) v += bias[gc];
            if (relu) v = fmaxf(v, 0.f);
            from_f(v, C[(size_t)gr * M + gc]);
        }
    }
}

template <typename TA, typename TC>
static inline void launch_gemm_valu(const TA* A, const float* W, const float* bias,
                                    TC* C, int nr, int K, int M, int relu, int addbias,
                                    hipStream_t stream) {
    dim3 grid((nr + BM - 1) / BM, (M + BN - 1) / BN);
    gemm_valu_kernel<TA, TC><<<grid, 256, 0, stream>>>(A, W, bias, C, nr, K, M, relu, addbias);
}

// ------------------------------ MFMA GEMM ---------------------------------
// C[nr x M] = A[nr x K](bf16) * Wt[M x K](bf16, pre-transposed) (+bias)(+relu)
// 128x128 tile, BK=32, 2x2 waves x 4x4 frags of v_mfma_f32_16x16x32_bf16.
__global__ __launch_bounds__(256) void gemm_mfma_kernel(
        const unsigned short* __restrict__ A, const unsigned short* __restrict__ Wt,
        const float* __restrict__ bias, unsigned short* __restrict__ C,
        int nr, int K, int M, int relu, int addbias) {
    __shared__ alignas(16) short As[128 * 32];
    __shared__ alignas(16) short Bs[128 * 32];
    const int tid  = threadIdx.x;
    const int w    = tid >> 6;
    const int lane = tid & 63;
    const int wr   = w >> 1;
    const int wc   = w & 1;
    const int row0 = blockIdx.x * 128;
    const int col0 = blockIdx.y * 128;

    f32x4 acc[4][4];
#pragma unroll
    for (int i = 0; i < 4; i++)
#pragma unroll
        for (int j = 0; j < 4; j++) acc[i][j] = {0.f, 0.f, 0.f, 0.f};

    const int lrow   = lane >> 2;
    const int lcolB  = (lane & 3) * 16;
    const int fm     = lane & 15;
    const int fq     = lane >> 4;

    for (int kk = 0; kk < K; kk += 32) {
#pragma unroll
        for (int i = 0; i < 2; i++) {
            int r = w * 32 + i * 16 + lrow;
            int grow = row0 + r;
            const char* g = (const char*)A + ((size_t)grow * K + kk) * 2 + lcolB;
            short* lds = &As[(w * 32 + i * 16) * 32];
            if (grow < nr) async_copy16(lds, g);
        }
#pragma unroll
        for (int i = 0; i < 2; i++) {
            int r = w * 32 + i * 16 + lrow;
            int gcol = col0 + r;
            const char* g = (const char*)Wt + ((size_t)gcol * K + kk) * 2 + lcolB;
            short* lds = &Bs[(w * 32 + i * 16) * 32];
            async_copy16(lds, g);
        }
        __syncthreads();

        short8 a[4], b[4];
#pragma unroll
        for (int i = 0; i < 4; i++) {
            a[i] = *(const short8*)&As[(wr * 64 + i * 16 + fm) * 32 + fq * 8];
            b[i] = *(const short8*)&Bs[(wc * 64 + i * 16 + fm) * 32 + fq * 8];
        }
#pragma unroll
        for (int mi = 0; mi < 4; mi++)
#pragma unroll
            for (int ni = 0; ni < 4; ni++)
                acc[mi][ni] = __builtin_amdgcn_mfma_f32_16x16x32_bf16(
                    a[mi], b[ni], acc[mi][ni], 0, 0, 0);
        __syncthreads();
    }

#pragma unroll
    for (int mi = 0; mi < 4; mi++) {
#pragma unroll
        for (int r = 0; r < 4; r++) {
            int row = row0 + wr * 64 + mi * 16 + fq * 4 + r;
            if (row >= nr) continue;
            size_t rb = (size_t)row * M;
#pragma unroll
            for (int ni = 0; ni < 4; ni++) {
                int col = col0 + wc * 64 + ni * 16 + fm;
                float v = acc[mi][ni][r];
                if (addbias) v += bias[col];
                if (relu) v = fmaxf(v, 0.f);
                C[rb + col] = f2b(v);
            }
        }
    }
}

static inline void launch_gemm_mfma(const unsigned short* A, const unsigned short* Wt,
                                    const float* bias, unsigned short* C,
                                    int nr, int K, int M, int relu, int addbias,
                                    hipStream_t stream) {
    dim3 grid((nr + 127) / 128, M / 128);
    gemm_mfma_kernel<<<grid, 256, 0, stream>>>(A, Wt, bias, C, nr, K, M, relu, addbias);
}

// ------------------------------- driver -----------------------------------

static inline size_t al256(size_t x) { return (x + 255) & ~(size_t)255; }

extern "C" void kernel_launch(void* const* d_in, const int* in_sizes, int n_in,
                              void* d_out, int out_size, void* d_ws, size_t ws_size,
                              hipStream_t stream) {
    const float* x  = (const float*)d_in[0];
    const int*   ei = (const int*)d_in[1];
    const int E = in_sizes[1] / 2;
    const int n = in_sizes[0] / 3;
    const int* rowv = ei;        // sources
    const int* colv = ei + E;    // targets

    const float* Wf[8]; const float* bt[8];
    for (int i = 0; i < 8; i++) { Wf[i] = (const float*)d_in[2 + 2 * i]; bt[i] = (const float*)d_in[3 + 2 * i]; }

    char* p = (char*)d_ws;
    size_t used = 0;
    auto carve = [&](size_t bytes) -> char* {
        char* r = p + used; used += al256(bytes); return r;
    };
    int*   deg    = (int*)carve((size_t)n * 4);
    float* dinv   = (float*)carve((size_t)n * 4);
    int*   rowptr = (int*)carve((size_t)(n + 1) * 4);
    int*   cursor = (int*)carve((size_t)(n + 1) * 4);
    int2*  es     = (int2*)carve((size_t)E * 8);   // packed (src, dinv[src])
    unsigned short* bufA = (unsigned short*)carve((size_t)n * 512 * 2);
    unsigned short* bufB = (unsigned short*)carve((size_t)n * 512 * 2);
    const size_t wt3e = 64 * 128, wt4e = 128 * 1024, wt5e = 1024 * 512, wt6e = 512 * 256;
    unsigned short* wt3 = (unsigned short*)carve((wt3e + wt4e + wt5e + wt6e) * 2);
    unsigned short* wt4 = wt3 + wt3e;
    unsigned short* wt5 = wt4 + wt4e;
    unsigned short* wt6 = wt5 + wt5e;
    size_t avail = (ws_size > used) ? (ws_size - used) : 0;
    int chunk = (int)(avail / (1024 * 2));
    if (chunk > n) chunk = n;
    chunk &= ~127;                  // multiple of 128 for clean MFMA tiles
    if (chunk < 2048) chunk = 2048; // floor
    char* tmp_raw = carve((size_t)chunk * 1024 * 2);
    unsigned short* tmpb = (unsigned short*)tmp_raw;
    float* tmpf = (float*)tmp_raw;   // reused: n x 2 fp32 (L7 pre-agg)

    const int EB = (E + TPB - 1) / TPB;
    const int NB = (n + TPB - 1) / TPB;
    const int NW = (n + 3) / 4;  // wave-per-node kernels, 4 waves/block

    // ---- graph preprocessing ----
    hipMemsetAsync(deg, 0, (size_t)n * 4, stream);
    count_deg_kernel<<<EB, TPB, 0, stream>>>(colv, deg, E, n);
    dinv_kernel<<<NB, TPB, 0, stream>>>(deg, dinv, n);
    scan_kernel<<<1, 1024, 0, stream>>>(deg, rowptr, cursor, n);
    fill_csr_kernel<<<EB, TPB, 0, stream>>>(rowv, colv, dinv, cursor, es, E, n);

    // ---- weight prep ----
    convert_wt_kernel<<<(int)((wt3e + 255) / 256), 256, 0, stream>>>(Wf[3], wt3, 64, 128);
    convert_wt_kernel<<<(int)((wt4e + 255) / 256), 256, 0, stream>>>(Wf[4], wt4, 128, 1024);
    convert_wt_kernel<<<(int)((wt5e + 255) / 256), 256, 0, stream>>>(Wf[5], wt5, 1024, 512);
    convert_wt_kernel<<<(int)((wt6e + 255) / 256), 256, 0, stream>>>(Wf[6], wt6, 512, 256);

    // ---- L0: fused agg(d=3) + (3->64 GEMM) + bias + relu -> bf16 ----
    agg_small_wave_kernel<3, 1><<<NW, TPB, 0, stream>>>(
        x, nullptr, bufA, rowptr, es, dinv, bt[0], Wf[0], n, 1);

    // ---- L1, L2: 64 -> 64 (agg-first, VALU gemm) ----
    agg_win_kernel<1><<<NW, TPB, 0, stream>>>(bufA, bufB, rowptr, es, dinv, nullptr, n, 64, 0, 0);
    launch_gemm_valu<__hip_bfloat16, __hip_bfloat16>((const __hip_bfloat16*)bufB, Wf[1], bt[1],
                                                     (__hip_bfloat16*)bufA, n, 64, 64, 1, 1, stream);
    agg_win_kernel<1><<<NW, TPB, 0, stream>>>(bufA, bufB, rowptr, es, dinv, nullptr, n, 64, 0, 0);
    launch_gemm_valu<__hip_bfloat16, __hip_bfloat16>((const __hip_bfloat16*)bufB, Wf[2], bt[2],
                                                     (__hip_bfloat16*)bufA, n, 64, 64, 1, 1, stream);

    // ---- L3: 64 -> 128 (agg-first, MFMA) ----
    agg_win_kernel<1><<<NW, TPB, 0, stream>>>(bufA, bufB, rowptr, es, dinv, nullptr, n, 64, 0, 0);
    launch_gemm_mfma(bufB, wt3, bt[3], bufA, n, 64, 128, 1, 1, stream);

    // ---- L4+L5 fused: agg on 128, then chunked (relu(.@W4+b4)) @ W5 ----
    agg_win_kernel<2><<<NW, TPB, 0, stream>>>(bufA, bufB, rowptr, es, dinv, nullptr, n, 128, 0, 0);
    for (int r0 = 0; r0 < n; r0 += chunk) {
        int ch = n - r0; if (ch > chunk) ch = chunk;
        launch_gemm_mfma(bufB + (size_t)r0 * 128, wt4, bt[4], tmpb, ch, 128, 1024, 1, 1, stream);
        launch_gemm_mfma(tmpb, wt5, nullptr, bufA + (size_t)r0 * 512, ch, 1024, 512, 0, 0, stream);
    }
    // L5 epilogue: agg on 512 in two 256-wide column passes (L3-resident WS)
    agg_win_kernel<4><<<NW, TPB, 0, stream>>>(bufA, bufB, rowptr, es, dinv, bt[5], n, 512, 0, 1);
    agg_win_kernel<4><<<NW, TPB, 0, stream>>>(bufA, bufB, rowptr, es, dinv, bt[5], n, 512, 256, 1);

    // ---- L6: 512 -> 256 (matmul-first MFMA, agg on 256, single pass) ----
    launch_gemm_mfma(bufB, wt6, nullptr, bufA, n, 512, 256, 0, 0, stream);
    agg_win_kernel<4><<<NW, TPB, 0, stream>>>(bufA, bufB, rowptr, es, dinv, bt[6], n, 256, 0, 1);

    // ---- L7: wave-dot GEMM (256->2), then agg d=2 + bias, no relu ----
    gemm_dot2_kernel<<<NW, TPB, 0, stream>>>(bufB, Wf[7], tmpf, n);
    agg_small_wave_kernel<2, 0><<<NW, TPB, 0, stream>>>(
        tmpf, (float*)d_out, nullptr, rowptr, es, dinv, bt[7], nullptr, n, 0);
}

// Round 6
// 2036.491 us; speedup vs baseline: 3.2454x; 1.0905x over previous
//
#include <hip/hip_runtime.h>
#include <hip/hip_bf16.h>
#include <cstdint>
#include <cstddef>

// ---------------------------------------------------------------------------
// GCNemb: 8-layer GCN. N=100000, E=3200000.
//   - CSR by target; agg(xW)==agg(x)W -> aggregate on smaller side.
//   - bf16 activation storage, fp32 arithmetic (absmax 4.6e-5 vs 6.56e-5 thr).
//   - r5: feature-window tiling (<=256 cols/pass) for L3-resident gathers;
//     packed (src,dinv) int2 per edge. [measured r5: aggs off the top-5]
//   - r6: parallel 3-phase scan (r5: single-block scan was 233us @ 0.15% occ);
//     L1/L2 agg+64x64 GEMM fused (wave-local LDS, no barrier).
// ---------------------------------------------------------------------------

#define TPB 256
#define SI 8                 // scan items per thread
#define STILE (TPB * SI)     // 2048 elements per scan block

typedef short short8 __attribute__((ext_vector_type(8)));
typedef float f32x4 __attribute__((ext_vector_type(4)));

__device__ __forceinline__ float b2f(unsigned short u) {
    union { unsigned int i; float f; } c; c.i = ((unsigned int)u) << 16; return c.f;
}
__device__ __forceinline__ unsigned short f2b(float f) {
    __hip_bfloat16 h = __float2bfloat16(f);
    union { __hip_bfloat16 h; unsigned short u; } c; c.h = h; return c.u;
}

__device__ __forceinline__ void async_copy16(void* lds, const void* g) {
    __builtin_amdgcn_global_load_lds(
        (const __attribute__((address_space(1))) void*)g,
        (__attribute__((address_space(3))) void*)lds,
        16, 0, 0);
}

// ------------------------------ graph prep --------------------------------

__global__ void count_deg_kernel(const int* __restrict__ col, int* __restrict__ deg,
                                 int E, int n) {
    int e = blockIdx.x * blockDim.x + threadIdx.x;
    if (e < E) {
        int c = col[e];
        if ((unsigned)c < (unsigned)n) atomicAdd(&deg[c], 1);
    }
}

__global__ void dinv_kernel(const int* __restrict__ deg, float* __restrict__ dinv, int n) {
    int i = blockIdx.x * blockDim.x + threadIdx.x;
    if (i < n) dinv[i] = 1.0f / sqrtf((float)(deg[i] + 1));  // +1 self-loop
}

// --- parallel exclusive scan of deg -> rowptr/cursor (3 phases) ---
__global__ __launch_bounds__(TPB) void scan_part1(const int* __restrict__ deg,
                                                  int* __restrict__ bsum, int n) {
    int t0 = blockIdx.x * STILE + threadIdx.x * SI;
    int s = 0;
#pragma unroll
    for (int j = 0; j < SI; j++) { int i = t0 + j; if (i < n) s += deg[i]; }
#pragma unroll
    for (int off = 32; off >= 1; off >>= 1) s += __shfl_xor(s, off);
    __shared__ int ws[TPB / 64];
    if ((threadIdx.x & 63) == 0) ws[threadIdx.x >> 6] = s;
    __syncthreads();
    if (threadIdx.x == 0) {
        int tot = 0;
        for (int i = 0; i < TPB / 64; i++) tot += ws[i];
        bsum[blockIdx.x] = tot;
    }
}

__global__ void scan_part2(int* __restrict__ bsum, int nb,
                           int* __restrict__ rowptr, int n) {
    __shared__ int sums[1024];
    int tid = threadIdx.x;
    int v = (tid < nb) ? bsum[tid] : 0;
    sums[tid] = v;
    __syncthreads();
    for (int off = 1; off < 1024; off <<= 1) {
        int t = (tid >= off) ? sums[tid - off] : 0;
        __syncthreads();
        sums[tid] += t;
        __syncthreads();
    }
    if (tid < nb) bsum[tid] = (tid == 0) ? 0 : sums[tid - 1];
    if (tid == 0) rowptr[n] = sums[1023];
}

__global__ __launch_bounds__(TPB) void scan_part3(const int* __restrict__ deg,
                                                  const int* __restrict__ bsum,
                                                  int* __restrict__ rowptr,
                                                  int* __restrict__ cursor, int n) {
    int tid = threadIdx.x;
    int lane = tid & 63, wv = tid >> 6;
    int t0 = blockIdx.x * STILE + tid * SI;
    int v[SI]; int s = 0;
#pragma unroll
    for (int j = 0; j < SI; j++) { int i = t0 + j; v[j] = (i < n) ? deg[i] : 0; s += v[j]; }
    int sc = s;  // inclusive wave scan
#pragma unroll
    for (int off = 1; off < 64; off <<= 1) {
        int t = __shfl_up(sc, off);
        if (lane >= off) sc += t;
    }
    __shared__ int wtot[TPB / 64];
    if (lane == 63) wtot[wv] = sc;
    __syncthreads();
    int woff = 0;
    for (int i = 0; i < wv; i++) woff += wtot[i];
    int off0 = bsum[blockIdx.x] + woff + (sc - s);
#pragma unroll
    for (int j = 0; j < SI; j++) {
        int i = t0 + j;
        if (i < n) { rowptr[i] = off0; cursor[i] = off0; }
        off0 += v[j];
    }
}

// fill CSR with packed (src, dinv[src]) per edge
__global__ void fill_csr_kernel(const int* __restrict__ row, const int* __restrict__ col,
                                const float* __restrict__ dinv,
                                int* __restrict__ cursor, int2* __restrict__ es,
                                int E, int n) {
    int e = blockIdx.x * blockDim.x + threadIdx.x;
    if (e < E) {
        int c = col[e];
        if ((unsigned)c < (unsigned)n) {
            int r = row[e];
            int pos = atomicAdd(&cursor[c], 1);
            if ((unsigned)pos < (unsigned)E) {
                es[pos] = make_int2(r, __float_as_int(dinv[r]));
            }
        }
    }
}

// weight prep: W[K x M] fp32 -> Wt[M x K] bf16
__global__ void convert_wt_kernel(const float* __restrict__ W, unsigned short* __restrict__ Wt,
                                  int K, int M) {
    int idx = blockIdx.x * blockDim.x + threadIdx.x;
    if (idx < K * M) {
        int k = idx / M, m = idx % M;
        Wt[(size_t)m * K + k] = f2b(W[idx]);
    }
}

// ----------------------------- aggregation --------------------------------

template <int VEC> struct Pack;
template <> struct Pack<1> { using T = unsigned short; };
template <> struct Pack<2> { using T = unsigned int; };
template <> struct Pack<4> { using T = uint2; };

// One wave per node; lane owns VEC contiguous bf16 features inside a column
// window starting at wb; full row stride is d. Edge (src,dinv) batch-loaded
// 64-at-a-time (8B coalesced), broadcast via shfl, gathers unrolled 4-wide.
template <int VEC>
__global__ __launch_bounds__(TPB) void agg_win_kernel(
        const unsigned short* __restrict__ x, unsigned short* __restrict__ out,
        const int* __restrict__ rowptr, const int2* __restrict__ es,
        const float* __restrict__ dinv, const float* __restrict__ bias,
        int n, int d, int wb, int relu) {
    using P = typename Pack<VEC>::T;
    int wid  = (blockIdx.x * blockDim.x + threadIdx.x) >> 6;
    int lane = threadIdx.x & 63;
    if (wid >= n) return;
    int start = rowptr[wid], end = rowptr[wid + 1];
    float acc0[VEC], acc1[VEC], acc2[VEC], acc3[VEC];
#pragma unroll
    for (int j = 0; j < VEC; j++) { acc0[j] = 0.f; acc1[j] = 0.f; acc2[j] = 0.f; acc3[j] = 0.f; }
    const int fo = wb + lane * VEC;
    union U { P v; unsigned short u[VEC]; };

    for (int base = start; base < end; base += 64) {
        int idx = base + lane;
        int clamped = (idx < end) ? idx : (end - 1);
        int2 ev = es[clamped];
        int   sv = ev.x;
        float dv = (idx < end) ? __int_as_float(ev.y) : 0.f;
        int cnt = end - base; if (cnt > 64) cnt = 64;
        int j = 0;
        for (; j + 4 <= cnt; j += 4) {
            int   s0 = __shfl(sv, j),     s1 = __shfl(sv, j + 1);
            int   s2 = __shfl(sv, j + 2), s3 = __shfl(sv, j + 3);
            float e0 = __shfl(dv, j),     e1 = __shfl(dv, j + 1);
            float e2 = __shfl(dv, j + 2), e3 = __shfl(dv, j + 3);
            U l0, l1, l2, l3;
            l0.v = *(const P*)(x + (size_t)s0 * d + fo);
            l1.v = *(const P*)(x + (size_t)s1 * d + fo);
            l2.v = *(const P*)(x + (size_t)s2 * d + fo);
            l3.v = *(const P*)(x + (size_t)s3 * d + fo);
#pragma unroll
            for (int q = 0; q < VEC; q++) {
                acc0[q] = fmaf(e0, b2f(l0.u[q]), acc0[q]);
                acc1[q] = fmaf(e1, b2f(l1.u[q]), acc1[q]);
                acc2[q] = fmaf(e2, b2f(l2.u[q]), acc2[q]);
                acc3[q] = fmaf(e3, b2f(l3.u[q]), acc3[q]);
            }
        }
        for (; j < cnt; j++) {
            int   s0 = __shfl(sv, j);
            float e0 = __shfl(dv, j);
            U l0; l0.v = *(const P*)(x + (size_t)s0 * d + fo);
#pragma unroll
            for (int q = 0; q < VEC; q++) acc0[q] = fmaf(e0, b2f(l0.u[q]), acc0[q]);
        }
    }

    float di = dinv[wid];
    U ls; ls.v = *(const P*)(x + (size_t)wid * d + fo);
    U st;
#pragma unroll
    for (int j = 0; j < VEC; j++) {
        float a = (acc0[j] + acc1[j]) + (acc2[j] + acc3[j]);
        float v = di * (a + di * b2f(ls.u[j]));
        if (bias) v += bias[fo + j];
        if (relu) v = fmaxf(v, 0.f);
        st.u[j] = f2b(v);
    }
    *(P*)(out + (size_t)wid * d + fo) = st.v;
}

// Fused: agg(64-wide) + [64x64 GEMM] + bias + relu -> bf16 (L1/L2).
// Wave per node; agg parked in wave-local LDS (no barrier: same-wave rw).
__global__ __launch_bounds__(TPB) void agg_gemm64_kernel(
        const unsigned short* __restrict__ x, unsigned short* __restrict__ out,
        const int* __restrict__ rowptr, const int2* __restrict__ es,
        const float* __restrict__ dinv, const float* __restrict__ W,
        const float* __restrict__ bias, int n) {
    __shared__ float Ws[64 * 64];
    __shared__ float aggs[TPB / 64][64];
    const int tid = threadIdx.x;
    for (int i = tid; i < 64 * 64; i += TPB) Ws[i] = W[i];
    __syncthreads();
    int wid  = (blockIdx.x * TPB + tid) >> 6;
    int lane = tid & 63;
    int wv   = tid >> 6;
    if (wid >= n) return;
    int start = rowptr[wid], end = rowptr[wid + 1];
    float acc0 = 0.f, acc1 = 0.f, acc2 = 0.f, acc3 = 0.f;
    for (int base = start; base < end; base += 64) {
        int idx = base + lane;
        int clamped = (idx < end) ? idx : (end - 1);
        int2 ev = es[clamped];
        int   sv = ev.x;
        float dv = (idx < end) ? __int_as_float(ev.y) : 0.f;
        int cnt = end - base; if (cnt > 64) cnt = 64;
        int j = 0;
        for (; j + 4 <= cnt; j += 4) {
            int   s0 = __shfl(sv, j),     s1 = __shfl(sv, j + 1);
            int   s2 = __shfl(sv, j + 2), s3 = __shfl(sv, j + 3);
            float e0 = __shfl(dv, j),     e1 = __shfl(dv, j + 1);
            float e2 = __shfl(dv, j + 2), e3 = __shfl(dv, j + 3);
            acc0 = fmaf(e0, b2f(x[(size_t)s0 * 64 + lane]), acc0);
            acc1 = fmaf(e1, b2f(x[(size_t)s1 * 64 + lane]), acc1);
            acc2 = fmaf(e2, b2f(x[(size_t)s2 * 64 + lane]), acc2);
            acc3 = fmaf(e3, b2f(x[(size_t)s3 * 64 + lane]), acc3);
        }
        for (; j < cnt; j++) {
            int   s0 = __shfl(sv, j);
            float e0 = __shfl(dv, j);
            acc0 = fmaf(e0, b2f(x[(size_t)s0 * 64 + lane]), acc0);
        }
    }
    float di = dinv[wid];
    float a = di * (((acc0 + acc1) + (acc2 + acc3)) + di * b2f(x[(size_t)wid * 64 + lane]));
    aggs[wv][lane] = a;
    // same-wave LDS write->read: lockstep + compiler lgkmcnt, no barrier
    float v = bias[lane];
#pragma unroll 8
    for (int j = 0; j < 64; j++) v = fmaf(aggs[wv][j], Ws[j * 64 + lane], v);
    v = fmaxf(v, 0.f);
    out[(size_t)wid * 64 + lane] = f2b(v);
}

// Wave-per-node, edge-parallel aggregation for tiny dims (fp32 x), with
// optional fused (D -> 64) GEMM + bias + relu -> bf16 output (L0 path).
template <int D, int FUSE64>
__global__ __launch_bounds__(TPB) void agg_small_wave_kernel(
        const float* __restrict__ x, float* __restrict__ outf,
        unsigned short* __restrict__ outb,
        const int* __restrict__ rowptr, const int2* __restrict__ es,
        const float* __restrict__ dinv, const float* __restrict__ bias,
        const float* __restrict__ W, int n, int relu) {
    int wid  = (blockIdx.x * blockDim.x + threadIdx.x) >> 6;
    int lane = threadIdx.x & 63;
    if (wid >= n) return;
    int start = rowptr[wid], end = rowptr[wid + 1];
    float acc[D];
#pragma unroll
    for (int j = 0; j < D; j++) acc[j] = 0.f;
    for (int e = start + lane; e < end; e += 64) {
        int2 ev = es[e];
        int s = ev.x;
        float ds = __int_as_float(ev.y);
#pragma unroll
        for (int j = 0; j < D; j++) acc[j] = fmaf(ds, x[(size_t)s * D + j], acc[j]);
    }
#pragma unroll
    for (int j = 0; j < D; j++) {
#pragma unroll
        for (int off = 32; off >= 1; off >>= 1) acc[j] += __shfl_xor(acc[j], off);
    }
    float di = dinv[wid];
    float aggv[D];
#pragma unroll
    for (int j = 0; j < D; j++) aggv[j] = di * (acc[j] + di * x[(size_t)wid * D + j]);

    if (FUSE64) {
        float v = bias[lane];
#pragma unroll
        for (int j = 0; j < D; j++) v = fmaf(aggv[j], W[j * 64 + lane], v);
        v = fmaxf(v, 0.f);
        outb[(size_t)wid * 64 + lane] = f2b(v);
    } else {
        if (lane < D) {
            float v = aggv[lane];
            if (bias) v += bias[lane];
            if (relu) v = fmaxf(v, 0.f);
            outf[(size_t)wid * D + lane] = v;
        }
    }
}

// Wave-per-node GEMM for L7: pre[n x 2] = A[n x 256](bf16) @ W[256 x 2](fp32)
__global__ __launch_bounds__(TPB) void gemm_dot2_kernel(
        const unsigned short* __restrict__ A, const float* __restrict__ W,
        float* __restrict__ pre, int n) {
    int wid  = (blockIdx.x * blockDim.x + threadIdx.x) >> 6;
    int lane = threadIdx.x & 63;
    if (wid >= n) return;
    union { uint2 v; unsigned short u[4]; } a;
    a.v = *(const uint2*)(A + (size_t)wid * 256 + lane * 4);
    float c0 = 0.f, c1 = 0.f;
#pragma unroll
    for (int j = 0; j < 4; j++) {
        float av = b2f(a.u[j]);
        c0 = fmaf(av, W[(lane * 4 + j) * 2 + 0], c0);
        c1 = fmaf(av, W[(lane * 4 + j) * 2 + 1], c1);
    }
#pragma unroll
    for (int off = 32; off >= 1; off >>= 1) {
        c0 += __shfl_xor(c0, off);
        c1 += __shfl_xor(c1, off);
    }
    if (lane == 0) { pre[(size_t)wid * 2 + 0] = c0; pre[(size_t)wid * 2 + 1] = c1; }
}

// ------------------------------ MFMA GEMM ---------------------------------
// C[nr x M] = A[nr x K](bf16) * Wt[M x K](bf16, pre-transposed) (+bias)(+relu)
// 128x128 tile, BK=32, 2x2 waves x 4x4 frags of v_mfma_f32_16x16x32_bf16.
__global__ __launch_bounds__(256) void gemm_mfma_kernel(
        const unsigned short* __restrict__ A, const unsigned short* __restrict__ Wt,
        const float* __restrict__ bias, unsigned short* __restrict__ C,
        int nr, int K, int M, int relu, int addbias) {
    __shared__ alignas(16) short As[128 * 32];
    __shared__ alignas(16) short Bs[128 * 32];
    const int tid  = threadIdx.x;
    const int w    = tid >> 6;
    const int lane = tid & 63;
    const int wr   = w >> 1;
    const int wc   = w & 1;
    const int row0 = blockIdx.x * 128;
    const int col0 = blockIdx.y * 128;

    f32x4 acc[4][4];
#pragma unroll
    for (int i = 0; i < 4; i++)
#pragma unroll
        for (int j = 0; j < 4; j++) acc[i][j] = {0.f, 0.f, 0.f, 0.f};

    const int lrow   = lane >> 2;
    const int lcolB  = (lane & 3) * 16;
    const int fm     = lane & 15;
    const int fq     = lane >> 4;

    for (int kk = 0; kk < K; kk += 32) {
#pragma unroll
        for (int i = 0; i < 2; i++) {
            int r = w * 32 + i * 16 + lrow;
            int grow = row0 + r;
            const char* g = (const char*)A + ((size_t)grow * K + kk) * 2 + lcolB;
            short* lds = &As[(w * 32 + i * 16) * 32];
            if (grow < nr) async_copy16(lds, g);
        }
#pragma unroll
        for (int i = 0; i < 2; i++) {
            int r = w * 32 + i * 16 + lrow;
            int gcol = col0 + r;
            const char* g = (const char*)Wt + ((size_t)gcol * K + kk) * 2 + lcolB;
            short* lds = &Bs[(w * 32 + i * 16) * 32];
            async_copy16(lds, g);
        }
        __syncthreads();

        short8 a[4], b[4];
#pragma unroll
        for (int i = 0; i < 4; i++) {
            a[i] = *(const short8*)&As[(wr * 64 + i * 16 + fm) * 32 + fq * 8];
            b[i] = *(const short8*)&Bs[(wc * 64 + i * 16 + fm) * 32 + fq * 8];
        }
#pragma unroll
        for (int mi = 0; mi < 4; mi++)
#pragma unroll
            for (int ni = 0; ni < 4; ni++)
                acc[mi][ni] = __builtin_amdgcn_mfma_f32_16x16x32_bf16(
                    a[mi], b[ni], acc[mi][ni], 0, 0, 0);
        __syncthreads();
    }

#pragma unroll
    for (int mi = 0; mi < 4; mi++) {
#pragma unroll
        for (int r = 0; r < 4; r++) {
            int row = row0 + wr * 64 + mi * 16 + fq * 4 + r;
            if (row >= nr) continue;
            size_t rb = (size_t)row * M;
#pragma unroll
            for (int ni = 0; ni < 4; ni++) {
                int col = col0 + wc * 64 + ni * 16 + fm;
                float v = acc[mi][ni][r];
                if (addbias) v += bias[col];
                if (relu) v = fmaxf(v, 0.f);
                C[rb + col] = f2b(v);
            }
        }
    }
}

static inline void launch_gemm_mfma(const unsigned short* A, const unsigned short* Wt,
                                    const float* bias, unsigned short* C,
                                    int nr, int K, int M, int relu, int addbias,
                                    hipStream_t stream) {
    dim3 grid((nr + 127) / 128, M / 128);
    gemm_mfma_kernel<<<grid, 256, 0, stream>>>(A, Wt, bias, C, nr, K, M, relu, addbias);
}

// ------------------------------- driver -----------------------------------

static inline size_t al256(size_t x) { return (x + 255) & ~(size_t)255; }

extern "C" void kernel_launch(void* const* d_in, const int* in_sizes, int n_in,
                              void* d_out, int out_size, void* d_ws, size_t ws_size,
                              hipStream_t stream) {
    const float* x  = (const float*)d_in[0];
    const int*   ei = (const int*)d_in[1];
    const int E = in_sizes[1] / 2;
    const int n = in_sizes[0] / 3;
    const int* rowv = ei;        // sources
    const int* colv = ei + E;    // targets

    const float* Wf[8]; const float* bt[8];
    for (int i = 0; i < 8; i++) { Wf[i] = (const float*)d_in[2 + 2 * i]; bt[i] = (const float*)d_in[3 + 2 * i]; }

    char* p = (char*)d_ws;
    size_t used = 0;
    auto carve = [&](size_t bytes) -> char* {
        char* r = p + used; used += al256(bytes); return r;
    };
    int*   deg    = (int*)carve((size_t)n * 4);
    float* dinv   = (float*)carve((size_t)n * 4);
    int*   rowptr = (int*)carve((size_t)(n + 1) * 4);
    int*   cursor = (int*)carve((size_t)(n + 1) * 4);
    int*   bsum   = (int*)carve(4096 * 4);
    int2*  es     = (int2*)carve((size_t)E * 8);   // packed (src, dinv[src])
    unsigned short* bufA = (unsigned short*)carve((size_t)n * 512 * 2);
    unsigned short* bufB = (unsigned short*)carve((size_t)n * 512 * 2);
    const size_t wt3e = 64 * 128, wt4e = 128 * 1024, wt5e = 1024 * 512, wt6e = 512 * 256;
    unsigned short* wt3 = (unsigned short*)carve((wt3e + wt4e + wt5e + wt6e) * 2);
    unsigned short* wt4 = wt3 + wt3e;
    unsigned short* wt5 = wt4 + wt4e;
    unsigned short* wt6 = wt5 + wt5e;
    size_t avail = (ws_size > used) ? (ws_size - used) : 0;
    int chunk = (int)(avail / (1024 * 2));
    if (chunk > n) chunk = n;
    chunk &= ~127;                  // multiple of 128 for clean MFMA tiles
    if (chunk < 2048) chunk = 2048; // floor
    char* tmp_raw = carve((size_t)chunk * 1024 * 2);
    unsigned short* tmpb = (unsigned short*)tmp_raw;
    float* tmpf = (float*)tmp_raw;   // reused: n x 2 fp32 (L7 pre-agg)

    const int EB = (E + TPB - 1) / TPB;
    const int NB = (n + TPB - 1) / TPB;
    const int NW = (n + 3) / 4;      // wave-per-node kernels, 4 waves/block
    const int SBK = (n + STILE - 1) / STILE;  // scan blocks

    // ---- graph preprocessing ----
    hipMemsetAsync(deg, 0, (size_t)n * 4, stream);
    count_deg_kernel<<<EB, TPB, 0, stream>>>(colv, deg, E, n);
    dinv_kernel<<<NB, TPB, 0, stream>>>(deg, dinv, n);
    scan_part1<<<SBK, TPB, 0, stream>>>(deg, bsum, n);
    scan_part2<<<1, 1024, 0, stream>>>(bsum, SBK, rowptr, n);
    scan_part3<<<SBK, TPB, 0, stream>>>(deg, bsum, rowptr, cursor, n);
    fill_csr_kernel<<<EB, TPB, 0, stream>>>(rowv, colv, dinv, cursor, es, E, n);

    // ---- weight prep ----
    convert_wt_kernel<<<(int)((wt3e + 255) / 256), 256, 0, stream>>>(Wf[3], wt3, 64, 128);
    convert_wt_kernel<<<(int)((wt4e + 255) / 256), 256, 0, stream>>>(Wf[4], wt4, 128, 1024);
    convert_wt_kernel<<<(int)((wt5e + 255) / 256), 256, 0, stream>>>(Wf[5], wt5, 1024, 512);
    convert_wt_kernel<<<(int)((wt6e + 255) / 256), 256, 0, stream>>>(Wf[6], wt6, 512, 256);

    // ---- L0: fused agg(d=3) + (3->64 GEMM) + bias + relu -> bf16 ----
    agg_small_wave_kernel<3, 1><<<NW, TPB, 0, stream>>>(
        x, nullptr, bufA, rowptr, es, dinv, bt[0], Wf[0], n, 1);

    // ---- L1, L2: fused agg + 64x64 GEMM + bias + relu ----
    agg_gemm64_kernel<<<NW, TPB, 0, stream>>>(bufA, bufB, rowptr, es, dinv, Wf[1], bt[1], n);
    agg_gemm64_kernel<<<NW, TPB, 0, stream>>>(bufB, bufA, rowptr, es, dinv, Wf[2], bt[2], n);

    // ---- L3: 64 -> 128 (agg-first, MFMA) ----
    agg_win_kernel<1><<<NW, TPB, 0, stream>>>(bufA, bufB, rowptr, es, dinv, nullptr, n, 64, 0, 0);
    launch_gemm_mfma(bufB, wt3, bt[3], bufA, n, 64, 128, 1, 1, stream);

    // ---- L4+L5 fused: agg on 128, then chunked (relu(.@W4+b4)) @ W5 ----
    agg_win_kernel<2><<<NW, TPB, 0, stream>>>(bufA, bufB, rowptr, es, dinv, nullptr, n, 128, 0, 0);
    for (int r0 = 0; r0 < n; r0 += chunk) {
        int ch = n - r0; if (ch > chunk) ch = chunk;
        launch_gemm_mfma(bufB + (size_t)r0 * 128, wt4, bt[4], tmpb, ch, 128, 1024, 1, 1, stream);
        launch_gemm_mfma(tmpb, wt5, nullptr, bufA + (size_t)r0 * 512, ch, 1024, 512, 0, 0, stream);
    }
    // L5 epilogue: agg on 512 in two 256-wide column passes (L3-resident WS)
    agg_win_kernel<4><<<NW, TPB, 0, stream>>>(bufA, bufB, rowptr, es, dinv, bt[5], n, 512, 0, 1);
    agg_win_kernel<4><<<NW, TPB, 0, stream>>>(bufA, bufB, rowptr, es, dinv, bt[5], n, 512, 256, 1);

    // ---- L6: 512 -> 256 (matmul-first MFMA, agg on 256, single pass) ----
    launch_gemm_mfma(bufB, wt6, nullptr, bufA, n, 512, 256, 0, 0, stream);
    agg_win_kernel<4><<<NW, TPB, 0, stream>>>(bufA, bufB, rowptr, es, dinv, bt[6], n, 256, 0, 1);

    // ---- L7: wave-dot GEMM (256->2), then agg d=2 + bias, no relu ----
    gemm_dot2_kernel<<<NW, TPB, 0, stream>>>(bufB, Wf[7], tmpf, n);
    agg_small_wave_kernel<2, 0><<<NW, TPB, 0, stream>>>(
        tmpf, (float*)d_out, nullptr, rowptr, es, dinv, bt[7], nullptr, n, 0);
}